// Round 1
// baseline (1453.413 us; speedup 1.0000x reference)
//
#include <hip/hip_runtime.h>
#include <cstddef>
#include <cstdint>

#define N_BATCH 16
#define C_IN    512
#define L       4096
#define KC      256
#define VC      512
#define NH      8
#define HK      32   // KC/NH
#define HV      64   // VC/NH
#define CTX_CHUNKS 16
#define CHUNK_L (L / CTX_CHUNKS)  // 256

// ---------------------------------------------------------------------------
// Kernel 1: KQV = [Wk;Wq;Wv] @ x + bias   (per batch: (1024x512)*(512x4096))
// kqv rows: 0..255 = K, 256..511 = Q, 512..1023 = V
// ---------------------------------------------------------------------------
__global__ __launch_bounds__(256) void k_qkv(
    const float* __restrict__ x,
    const float* __restrict__ Wk, const float* __restrict__ bk,
    const float* __restrict__ Wq, const float* __restrict__ bq,
    const float* __restrict__ Wv, const float* __restrict__ bv,
    float* __restrict__ kqv)
{
  const int n  = blockIdx.z;
  const int oy = blockIdx.y;   // 16 row tiles of 64
  const int lx = blockIdx.x;   // 64 col tiles of 64
  const int tid = threadIdx.x;
  const int tx = tid & 15, ty = tid >> 4;

  const int orow = oy * 64;
  const float* W; const float* bias;
  if (orow < 256)      { W = Wk + (size_t)orow * C_IN;         bias = bk + orow; }
  else if (orow < 512) { W = Wq + (size_t)(orow - 256) * C_IN; bias = bq + (orow - 256); }
  else                 { W = Wv + (size_t)(orow - 512) * C_IN; bias = bv + (orow - 512); }

  // 68-float row stride: 272B = multiple of 16B -> aligned float4 LDS reads
  __shared__ __align__(16) float As[32][68];   // [c][o]
  __shared__ __align__(16) float Bs[32][68];   // [c][l]

  const float* xp = x + (size_t)n * C_IN * L + (size_t)lx * 64;

  float acc[4][4] = {};

  for (int k0 = 0; k0 < C_IN; k0 += 32) {
    #pragma unroll
    for (int i = 0; i < 8; ++i) {
      int idx = tid + i * 256;
      int o = idx >> 5, c = idx & 31;
      As[c][o] = W[(size_t)o * C_IN + k0 + c];
    }
    #pragma unroll
    for (int i = 0; i < 8; ++i) {
      int idx = tid + i * 256;
      int c = idx >> 6, l = idx & 63;
      Bs[c][l] = xp[(size_t)(k0 + c) * L + l];
    }
    __syncthreads();
    #pragma unroll
    for (int kk = 0; kk < 32; ++kk) {
      float4 a = *(const float4*)&As[kk][ty * 4];
      float4 b = *(const float4*)&Bs[kk][tx * 4];
      float av[4] = {a.x, a.y, a.z, a.w};
      float bv4[4] = {b.x, b.y, b.z, b.w};
      #pragma unroll
      for (int i = 0; i < 4; ++i)
        #pragma unroll
        for (int j = 0; j < 4; ++j)
          acc[i][j] += av[i] * bv4[j];
    }
    __syncthreads();
  }

  float* outp = kqv + ((size_t)n * 1024 + orow) * L + (size_t)lx * 64;
  #pragma unroll
  for (int i = 0; i < 4; ++i) {
    int o = ty * 4 + i;
    float bo = bias[o];
    #pragma unroll
    for (int j = 0; j < 4; ++j)
      outp[(size_t)o * L + tx * 4 + j] = acc[i][j] + bo;
  }
}

// ---------------------------------------------------------------------------
// Reductions
// ---------------------------------------------------------------------------
__device__ inline float blockReduceMax(float v, float* red) {
  #pragma unroll
  for (int off = 32; off > 0; off >>= 1)
    v = fmaxf(v, __shfl_down(v, off, 64));
  int tid = threadIdx.x;
  if ((tid & 63) == 0) red[tid >> 6] = v;
  __syncthreads();
  return fmaxf(fmaxf(red[0], red[1]), fmaxf(red[2], red[3]));
}
__device__ inline float blockReduceSum(float v, float* red) {
  #pragma unroll
  for (int off = 32; off > 0; off >>= 1)
    v += __shfl_down(v, off, 64);
  int tid = threadIdx.x;
  if ((tid & 63) == 0) red[tid >> 6] = v;
  __syncthreads();
  return red[0] + red[1] + red[2] + red[3];
}

// ---------------------------------------------------------------------------
// Kernel 2: K softmax stats over L per (n, row).  kmax, kinv = 1/sum(exp)
// ---------------------------------------------------------------------------
__global__ __launch_bounds__(256) void k_kstats(const float* __restrict__ kqv,
                                                float* __restrict__ kmax,
                                                float* __restrict__ kinv)
{
  const int r = blockIdx.x;   // 0..255
  const int n = blockIdx.y;
  const float* row = kqv + ((size_t)n * 1024 + r) * L;
  __shared__ float red1[4];
  __shared__ float red2[4];
  const int tid = threadIdx.x;
  float m = -3.0e38f;
  for (int i = tid; i < L; i += 256) m = fmaxf(m, row[i]);
  m = blockReduceMax(m, red1);
  float s = 0.f;
  for (int i = tid; i < L; i += 256) s += __expf(row[i] - m);
  s = blockReduceSum(s, red2);
  if (tid == 0) { kmax[n * KC + r] = m; kinv[n * KC + r] = 1.0f / s; }
}

// ---------------------------------------------------------------------------
// Kernel 3: Q softmax stats over the 32 head-channels per (n,h,l)
// ---------------------------------------------------------------------------
__global__ __launch_bounds__(256) void k_qstats(const float* __restrict__ kqv,
                                                float* __restrict__ qmax,
                                                float* __restrict__ qinv)
{
  int t = blockIdx.x * 256 + threadIdx.x;   // N*NH*L = 524288
  int l = t & (L - 1);
  int h = (t >> 12) & 7;
  int n = t >> 15;
  const float* base = kqv + ((size_t)n * 1024 + KC + h * HK) * L + l;
  float q[HK];
  #pragma unroll
  for (int k = 0; k < HK; ++k) q[k] = base[(size_t)k * L];
  float m = -3.0e38f;
  #pragma unroll
  for (int k = 0; k < HK; ++k) m = fmaxf(m, q[k]);
  float s = 0.f;
  #pragma unroll
  for (int k = 0; k < HK; ++k) s += __expf(q[k] - m);
  qmax[t] = m;
  qinv[t] = 1.0f / s;
}

// ---------------------------------------------------------------------------
// Kernel 4: context partials: ctx[v][k] = sum_l V[v,l] * softmax(K)[k,l]
// grid: (chunk, nh); each block does a 64x32 tile over CHUNK_L positions.
// ---------------------------------------------------------------------------
__global__ __launch_bounds__(256) void k_ctx(const float* __restrict__ kqv,
                                             const float* __restrict__ kmax,
                                             const float* __restrict__ kinv,
                                             float* __restrict__ ctxpart)
{
  const int chunk = blockIdx.x;   // 16
  const int nh    = blockIdx.y;   // 128 = n*8+h
  const int n = nh >> 3, h = nh & 7;
  const int tid = threadIdx.x;
  const int k  = tid & 31;
  const int vb = tid >> 5;        // 0..7 -> v = vb*8 + m

  __shared__ __align__(16) float Ks[32][68];
  __shared__ __align__(16) float Vs[64][68];
  __shared__ float km[32], kv[32];

  if (tid < 32) { km[tid] = kmax[nh * 32 + tid]; kv[tid] = kinv[nh * 32 + tid]; }
  __syncthreads();

  const float* Kp = kqv + ((size_t)n * 1024 + h * HK) * L + (size_t)chunk * CHUNK_L;
  const float* Vp = kqv + ((size_t)n * 1024 + 512 + h * HV) * L + (size_t)chunk * CHUNK_L;

  float acc[8] = {};

  for (int l0 = 0; l0 < CHUNK_L; l0 += 64) {
    #pragma unroll
    for (int i = 0; i < 8; ++i) {   // K tile 32x64, normalized on the fly
      int idx = tid + i * 256;
      int kk = idx >> 6, ll = idx & 63;
      Ks[kk][ll] = __expf(Kp[(size_t)kk * L + l0 + ll] - km[kk]) * kv[kk];
    }
    #pragma unroll
    for (int i = 0; i < 16; ++i) {  // V tile 64x64
      int idx = tid + i * 256;
      int vv = idx >> 6, ll = idx & 63;
      Vs[vv][ll] = Vp[(size_t)vv * L + l0 + ll];
    }
    __syncthreads();
    #pragma unroll
    for (int ll = 0; ll < 64; ll += 4) {
      float4 kf = *(const float4*)&Ks[k][ll];
      #pragma unroll
      for (int m = 0; m < 8; ++m) {
        float4 vf = *(const float4*)&Vs[vb * 8 + m][ll];
        acc[m] += vf.x * kf.x + vf.y * kf.y + vf.z * kf.z + vf.w * kf.w;
      }
    }
    __syncthreads();
  }

  float* outp = ctxpart + ((size_t)nh * CTX_CHUNKS + chunk) * (HV * HK);
  #pragma unroll
  for (int m = 0; m < 8; ++m)
    outp[(vb * 8 + m) * HK + k] = acc[m];
}

// ---------------------------------------------------------------------------
// Kernel 5: reduce ctx partials; fold We:  M[o][h*32+k] = sum_v We[o][h*64+v]*ctx[v][k]
// grid: (h, n)
// ---------------------------------------------------------------------------
__global__ __launch_bounds__(256) void k_m(const float* __restrict__ ctxpart,
                                           const float* __restrict__ We,
                                           float* __restrict__ Mbuf)
{
  const int h = blockIdx.x;   // 8
  const int n = blockIdx.y;   // 16
  const int nh = n * 8 + h;
  const int tid = threadIdx.x;
  __shared__ float ctx[64][32];

  #pragma unroll
  for (int i = 0; i < 8; ++i) {
    int e = tid + i * 256;    // e = v*32 + k
    float s = 0.f;
    for (int c = 0; c < CTX_CHUNKS; ++c)
      s += ctxpart[((size_t)nh * CTX_CHUNKS + c) * (HV * HK) + e];
    ((float*)ctx)[e] = s;
  }
  __syncthreads();

  const int k  = tid & 31;
  const int og = tid >> 5;    // 0..7 -> o = og*64 + j
  for (int j = 0; j < 64; ++j) {
    int o = og * 64 + j;
    const float* we = We + (size_t)o * VC + h * HV;
    float s = 0.f;
    #pragma unroll
    for (int v = 0; v < 64; ++v) s += we[v] * ctx[v][k];
    Mbuf[((size_t)n * 512 + o) * 256 + h * 32 + k] = s;
  }
}

// ---------------------------------------------------------------------------
// Kernel 6: out = x + be + M @ softmax_ch(Q)   (per n: (512x256)*(256x4096))
// Q softmax applied during B-tile load; BK=32 aligns k-tile with head kt.
// ---------------------------------------------------------------------------
__global__ __launch_bounds__(256) void k_final(
    const float* __restrict__ Mbuf,
    const float* __restrict__ kqv,
    const float* __restrict__ qmax,
    const float* __restrict__ qinv,
    const float* __restrict__ x,
    const float* __restrict__ be,
    float* __restrict__ out)
{
  const int n  = blockIdx.z;
  const int oy = blockIdx.y;   // 8 tiles of 64 o
  const int lx = blockIdx.x;   // 64 tiles of 64 l
  const int tid = threadIdx.x;
  const int tx = tid & 15, ty = tid >> 4;

  __shared__ __align__(16) float As[32][68];
  __shared__ __align__(16) float Bs[32][68];

  float acc[4][4] = {};
  const float* Mp = Mbuf + ((size_t)n * 512 + oy * 64) * 256;
  const float* Qp = kqv + ((size_t)n * 1024 + KC) * L + (size_t)lx * 64;
  const float* qm = qmax + (size_t)n * NH * L + (size_t)lx * 64;
  const float* qi = qinv + (size_t)n * NH * L + (size_t)lx * 64;

  for (int kt = 0; kt < 8; ++kt) {   // head = kt
    #pragma unroll
    for (int i = 0; i < 8; ++i) {
      int idx = tid + i * 256;
      int o = idx >> 5, c = idx & 31;
      As[c][o] = Mp[(size_t)o * 256 + kt * 32 + c];
    }
    #pragma unroll
    for (int i = 0; i < 8; ++i) {
      int idx = tid + i * 256;
      int c = idx >> 6, l = idx & 63;
      float qv = Qp[(size_t)(kt * 32 + c) * L + l];
      Bs[c][l] = __expf(qv - qm[(size_t)kt * L + l]) * qi[(size_t)kt * L + l];
    }
    __syncthreads();
    #pragma unroll
    for (int kk = 0; kk < 32; ++kk) {
      float4 a = *(const float4*)&As[kk][ty * 4];
      float4 b = *(const float4*)&Bs[kk][tx * 4];
      float av[4] = {a.x, a.y, a.z, a.w};
      float bv4[4] = {b.x, b.y, b.z, b.w};
      #pragma unroll
      for (int i = 0; i < 4; ++i)
        #pragma unroll
        for (int j = 0; j < 4; ++j)
          acc[i][j] += av[i] * bv4[j];
    }
    __syncthreads();
  }

  const float* xp = x + ((size_t)n * 512 + oy * 64) * L + (size_t)lx * 64;
  float* op = out + ((size_t)n * 512 + oy * 64) * L + (size_t)lx * 64;
  #pragma unroll
  for (int i = 0; i < 4; ++i) {
    int o = ty * 4 + i;
    float bo = be[oy * 64 + o];
    #pragma unroll
    for (int j = 0; j < 4; ++j) {
      int l = tx * 4 + j;
      op[(size_t)o * L + l] = xp[(size_t)o * L + l] + acc[i][j] + bo;
    }
  }
}

// ---------------------------------------------------------------------------
extern "C" void kernel_launch(void* const* d_in, const int* in_sizes, int n_in,
                              void* d_out, int out_size, void* d_ws, size_t ws_size,
                              hipStream_t stream)
{
  const float* x  = (const float*)d_in[0];
  const float* Wk = (const float*)d_in[1];
  const float* bk = (const float*)d_in[2];
  const float* Wq = (const float*)d_in[3];
  const float* bq = (const float*)d_in[4];
  const float* Wv = (const float*)d_in[5];
  const float* bv = (const float*)d_in[6];
  const float* We = (const float*)d_in[7];
  const float* be = (const float*)d_in[8];
  float* out = (float*)d_out;

  char* ws = (char*)d_ws;
  size_t off = 0;
  float* kqv  = (float*)(ws + off); off += (size_t)N_BATCH * 1024 * L * 4;   // 268 MB
  float* kmax = (float*)(ws + off); off += (size_t)N_BATCH * KC * 4;
  float* kinv = (float*)(ws + off); off += (size_t)N_BATCH * KC * 4;
  float* qmax = (float*)(ws + off); off += (size_t)N_BATCH * NH * L * 4;
  float* qinv = (float*)(ws + off); off += (size_t)N_BATCH * NH * L * 4;
  float* ctxp = (float*)(ws + off); off += (size_t)N_BATCH * NH * CTX_CHUNKS * HV * HK * 4;
  float* Mbuf = (float*)(ws + off); off += (size_t)N_BATCH * 512 * 256 * 4;

  k_qkv  <<<dim3(64, 16, N_BATCH), 256, 0, stream>>>(x, Wk, bk, Wq, bq, Wv, bv, kqv);
  k_kstats<<<dim3(KC, N_BATCH),    256, 0, stream>>>(kqv, kmax, kinv);
  k_qstats<<<dim3((N_BATCH * NH * L) / 256), 256, 0, stream>>>(kqv, qmax, qinv);
  k_ctx  <<<dim3(CTX_CHUNKS, N_BATCH * NH), 256, 0, stream>>>(kqv, kmax, kinv, ctxp);
  k_m    <<<dim3(NH, N_BATCH),     256, 0, stream>>>(ctxp, We, Mbuf);
  k_final<<<dim3(64, 8, N_BATCH),  256, 0, stream>>>(Mbuf, kqv, qmax, qinv, x, be, out);
}

// Round 2
// 699.939 us; speedup vs baseline: 2.0765x; 2.0765x over previous
//
#include <hip/hip_runtime.h>
#include <cstddef>
#include <cstdint>

#define N_BATCH 16
#define C_IN    512
#define L       4096
#define KC      256
#define VC      512
#define NH      8
#define HK      32   // KC/NH
#define HV      64   // VC/NH
#define CTX_CHUNKS 16
#define CHUNK_L (L / CTX_CHUNKS)  // 256

using f32x4 = __attribute__((ext_vector_type(4))) float;
using s16x8 = __attribute__((ext_vector_type(8))) short;

// round-to-nearest-even fp32 -> bf16 bits
static __device__ inline ushort f2bf(float f) {
  uint32_t u = __float_as_uint(f);
  uint32_t r = (u + 0x7FFFu + ((u >> 16) & 1u)) >> 16;
  return (ushort)r;
}

// ---------------------------------------------------------------------------
// Prep 1: combined bf16 weight matrix Wb[1024][512] (rows 0..255 K, 256..511 Q,
// 512..1023 V) + combined bias bb[1024]
// ---------------------------------------------------------------------------
__global__ __launch_bounds__(256) void k_prep_w(
    const float* __restrict__ Wk, const float* __restrict__ bk,
    const float* __restrict__ Wq, const float* __restrict__ bq,
    const float* __restrict__ Wv, const float* __restrict__ bv,
    ushort* __restrict__ Wb, float* __restrict__ bb)
{
  const int o = blockIdx.x;          // 1024
  const float* src; const float* bsrc; int oo;
  if (o < 256)      { src = Wk + (size_t)o * C_IN;         bsrc = bk; oo = o; }
  else if (o < 512) { src = Wq + (size_t)(o - 256) * C_IN; bsrc = bq; oo = o - 256; }
  else              { src = Wv + (size_t)(o - 512) * C_IN; bsrc = bv; oo = o - 512; }
  const int t = threadIdx.x;         // 256 threads, 2 elems each
  Wb[(size_t)o * C_IN + t * 2]     = f2bf(src[t * 2]);
  Wb[(size_t)o * C_IN + t * 2 + 1] = f2bf(src[t * 2 + 1]);
  if (t == 0) bb[o] = bsrc[oo];
}

// ---------------------------------------------------------------------------
// Prep 2: transpose+cast x (n,512,4096) f32 -> xT (n,4096,512) bf16
// 64x64 tiles via LDS, coalesced both sides.
// ---------------------------------------------------------------------------
__global__ __launch_bounds__(256) void k_prep_x(const float* __restrict__ x,
                                                ushort* __restrict__ xT)
{
  __shared__ float t[64][65];
  const int n = blockIdx.z, cy = blockIdx.y, lx = blockIdx.x;
  const float* xp = x + ((size_t)n * C_IN + cy * 64) * L + (size_t)lx * 64;
  const int ll = threadIdx.x & 63, c0 = threadIdx.x >> 6;
  #pragma unroll
  for (int i = 0; i < 16; ++i) {
    int cc = c0 + i * 4;
    t[cc][ll] = xp[(size_t)cc * L + ll];
  }
  __syncthreads();
  ushort* op = xT + ((size_t)n * L + lx * 64) * C_IN + cy * 64;
  const int cp = (threadIdx.x & 31) * 2, l0 = threadIdx.x >> 5;
  #pragma unroll
  for (int i = 0; i < 8; ++i) {
    int lr = l0 + i * 8;
    uint32_t pack = (uint32_t)f2bf(t[cp][lr]) | ((uint32_t)f2bf(t[cp + 1][lr]) << 16);
    *(uint32_t*)(op + (size_t)lr * C_IN + cp) = pack;
  }
}

// ---------------------------------------------------------------------------
// Kernel 1: KQV = Wb @ x + bias via bf16 MFMA (m97 structure).
// Per batch: (1024 x 512) * (512 x 4096) -> kqv fp32 (n,1024,4096).
// 128x128 tile, BK=32, 4 waves (2x2), each wave 64x64 = 4x4 frags 16x16x32.
// ---------------------------------------------------------------------------
#define BM 128
#define BN 128
#define BK 32

__global__ __launch_bounds__(256) void k_qkv_mfma(
    const ushort* __restrict__ Wb,   // [1024][512] bf16
    const ushort* __restrict__ xT,   // [n][4096][512] bf16
    const float* __restrict__ bb,    // [1024]
    float* __restrict__ kqv)         // [n][1024][4096] f32
{
  const int n  = blockIdx.z;
  const int oy = blockIdx.y;   // 8 row tiles
  const int lx = blockIdx.x;   // 32 col tiles
  const int tid  = threadIdx.x;
  const int wave = tid >> 6, lane = tid & 63;
  const int wr = wave >> 1, wc = wave & 1;

  __shared__ __align__(16) ushort As[BM * BK];  // [o][c] linear
  __shared__ __align__(16) ushort Bs[BN * BK];  // [l][c] linear

  f32x4 acc[4][4] = {};

  const ushort* gA = Wb + (size_t)(oy * BM) * C_IN;
  const ushort* gB = xT + ((size_t)n * L + lx * BN) * C_IN;

  const int r0 = wave * 32;              // this wave's 32-row staging chunk
  const int lrow = lane >> 2;            // 0..15 within 16-row issue
  const int c8   = (lane & 3) * 8;       // 8-elem column chunk

  for (int k0 = 0; k0 < C_IN; k0 += BK) {
    #pragma unroll
    for (int i = 0; i < 2; ++i) {
      int row = r0 + i * 16 + lrow;
      __builtin_amdgcn_global_load_lds(
          (const __attribute__((address_space(1))) uint32_t*)(gA + (size_t)row * C_IN + k0 + c8),
          (__attribute__((address_space(3))) uint32_t*)(As + (r0 + i * 16) * BK),
          16, 0, 0);
      __builtin_amdgcn_global_load_lds(
          (const __attribute__((address_space(1))) uint32_t*)(gB + (size_t)row * C_IN + k0 + c8),
          (__attribute__((address_space(3))) uint32_t*)(Bs + (r0 + i * 16) * BK),
          16, 0, 0);
    }
    __syncthreads();

    s16x8 af[4], bf[4];
    #pragma unroll
    for (int m = 0; m < 4; ++m)
      af[m] = *(const s16x8*)&As[(wr * 64 + m * 16 + (lane & 15)) * BK + (lane >> 4) * 8];
    #pragma unroll
    for (int nn = 0; nn < 4; ++nn)
      bf[nn] = *(const s16x8*)&Bs[(wc * 64 + nn * 16 + (lane & 15)) * BK + (lane >> 4) * 8];
    #pragma unroll
    for (int m = 0; m < 4; ++m)
      #pragma unroll
      for (int nn = 0; nn < 4; ++nn)
        acc[m][nn] = __builtin_amdgcn_mfma_f32_16x16x32_bf16(af[m], bf[nn], acc[m][nn], 0, 0, 0);
    __syncthreads();
  }

  float* outp = kqv + ((size_t)n * 1024 + oy * BM) * L + (size_t)lx * BN;
  #pragma unroll
  for (int m = 0; m < 4; ++m) {
    int oo = wr * 64 + m * 16 + (lane >> 4) * 4;
    #pragma unroll
    for (int nn = 0; nn < 4; ++nn) {
      int ll = wc * 64 + nn * 16 + (lane & 15);
      f32x4 v = acc[m][nn];
      #pragma unroll
      for (int r = 0; r < 4; ++r) {
        int o = oo + r;
        outp[(size_t)o * L + ll] = v[r] + bb[oy * BM + o];
      }
    }
  }
}

// ---------------------------------------------------------------------------
// Reductions
// ---------------------------------------------------------------------------
__device__ inline float blockReduceMax(float v, float* red) {
  #pragma unroll
  for (int off = 32; off > 0; off >>= 1)
    v = fmaxf(v, __shfl_down(v, off, 64));
  int tid = threadIdx.x;
  if ((tid & 63) == 0) red[tid >> 6] = v;
  __syncthreads();
  return fmaxf(fmaxf(red[0], red[1]), fmaxf(red[2], red[3]));
}
__device__ inline float blockReduceSum(float v, float* red) {
  #pragma unroll
  for (int off = 32; off > 0; off >>= 1)
    v += __shfl_down(v, off, 64);
  int tid = threadIdx.x;
  if ((tid & 63) == 0) red[tid >> 6] = v;
  __syncthreads();
  return red[0] + red[1] + red[2] + red[3];
}

// ---------------------------------------------------------------------------
// Kernel 2: K softmax stats over L per (n, row)
// ---------------------------------------------------------------------------
__global__ __launch_bounds__(256) void k_kstats(const float* __restrict__ kqv,
                                                float* __restrict__ kmax,
                                                float* __restrict__ kinv)
{
  const int r = blockIdx.x;
  const int n = blockIdx.y;
  const float* row = kqv + ((size_t)n * 1024 + r) * L;
  __shared__ float red1[4];
  __shared__ float red2[4];
  const int tid = threadIdx.x;
  float m = -3.0e38f;
  for (int i = tid; i < L; i += 256) m = fmaxf(m, row[i]);
  m = blockReduceMax(m, red1);
  float s = 0.f;
  for (int i = tid; i < L; i += 256) s += __expf(row[i] - m);
  s = blockReduceSum(s, red2);
  if (tid == 0) { kmax[n * KC + r] = m; kinv[n * KC + r] = 1.0f / s; }
}

// ---------------------------------------------------------------------------
// Kernel 3: Q softmax stats over the 32 head-channels per (n,h,l)
// ---------------------------------------------------------------------------
__global__ __launch_bounds__(256) void k_qstats(const float* __restrict__ kqv,
                                                float* __restrict__ qmax,
                                                float* __restrict__ qinv)
{
  int t = blockIdx.x * 256 + threadIdx.x;
  int l = t & (L - 1);
  int h = (t >> 12) & 7;
  int n = t >> 15;
  const float* base = kqv + ((size_t)n * 1024 + KC + h * HK) * L + l;
  float q[HK];
  #pragma unroll
  for (int k = 0; k < HK; ++k) q[k] = base[(size_t)k * L];
  float m = -3.0e38f;
  #pragma unroll
  for (int k = 0; k < HK; ++k) m = fmaxf(m, q[k]);
  float s = 0.f;
  #pragma unroll
  for (int k = 0; k < HK; ++k) s += __expf(q[k] - m);
  qmax[t] = m;
  qinv[t] = 1.0f / s;
}

// ---------------------------------------------------------------------------
// Kernel 4: context partials: ctx[v][k] = sum_l V[v,l] * softmax(K)[k,l]
// ---------------------------------------------------------------------------
__global__ __launch_bounds__(256) void k_ctx(const float* __restrict__ kqv,
                                             const float* __restrict__ kmax,
                                             const float* __restrict__ kinv,
                                             float* __restrict__ ctxpart)
{
  const int chunk = blockIdx.x;
  const int nh    = blockIdx.y;
  const int n = nh >> 3, h = nh & 7;
  const int tid = threadIdx.x;
  const int k  = tid & 31;
  const int vb = tid >> 5;

  __shared__ __align__(16) float Ks[32][68];
  __shared__ __align__(16) float Vs[64][68];
  __shared__ float km[32], kv[32];

  if (tid < 32) { km[tid] = kmax[nh * 32 + tid]; kv[tid] = kinv[nh * 32 + tid]; }
  __syncthreads();

  const float* Kp = kqv + ((size_t)n * 1024 + h * HK) * L + (size_t)chunk * CHUNK_L;
  const float* Vp = kqv + ((size_t)n * 1024 + 512 + h * HV) * L + (size_t)chunk * CHUNK_L;

  float acc[8] = {};

  for (int l0 = 0; l0 < CHUNK_L; l0 += 64) {
    #pragma unroll
    for (int i = 0; i < 8; ++i) {
      int idx = tid + i * 256;
      int kk = idx >> 6, ll = idx & 63;
      Ks[kk][ll] = __expf(Kp[(size_t)kk * L + l0 + ll] - km[kk]) * kv[kk];
    }
    #pragma unroll
    for (int i = 0; i < 16; ++i) {
      int idx = tid + i * 256;
      int vv = idx >> 6, ll = idx & 63;
      Vs[vv][ll] = Vp[(size_t)vv * L + l0 + ll];
    }
    __syncthreads();
    #pragma unroll
    for (int ll = 0; ll < 64; ll += 4) {
      float4 kf = *(const float4*)&Ks[k][ll];
      #pragma unroll
      for (int m = 0; m < 8; ++m) {
        float4 vf = *(const float4*)&Vs[vb * 8 + m][ll];
        acc[m] += vf.x * kf.x + vf.y * kf.y + vf.z * kf.z + vf.w * kf.w;
      }
    }
    __syncthreads();
  }

  float* outp = ctxpart + ((size_t)nh * CTX_CHUNKS + chunk) * (HV * HK);
  #pragma unroll
  for (int m = 0; m < 8; ++m)
    outp[(vb * 8 + m) * HK + k] = acc[m];
}

// ---------------------------------------------------------------------------
// Kernel 5: reduce ctx partials; fold We
// ---------------------------------------------------------------------------
__global__ __launch_bounds__(256) void k_m(const float* __restrict__ ctxpart,
                                           const float* __restrict__ We,
                                           float* __restrict__ Mbuf)
{
  const int h = blockIdx.x;
  const int n = blockIdx.y;
  const int nh = n * 8 + h;
  const int tid = threadIdx.x;
  __shared__ float ctx[64][32];

  #pragma unroll
  for (int i = 0; i < 8; ++i) {
    int e = tid + i * 256;
    float s = 0.f;
    for (int c = 0; c < CTX_CHUNKS; ++c)
      s += ctxpart[((size_t)nh * CTX_CHUNKS + c) * (HV * HK) + e];
    ((float*)ctx)[e] = s;
  }
  __syncthreads();

  const int k  = tid & 31;
  const int og = tid >> 5;
  for (int j = 0; j < 64; ++j) {
    int o = og * 64 + j;
    const float* we = We + (size_t)o * VC + h * HV;
    float s = 0.f;
    #pragma unroll
    for (int v = 0; v < 64; ++v) s += we[v] * ctx[v][k];
    Mbuf[((size_t)n * 512 + o) * 256 + h * 32 + k] = s;
  }
}

// ---------------------------------------------------------------------------
// Kernel 6: out = x + be + M @ softmax_ch(Q)
// ---------------------------------------------------------------------------
__global__ __launch_bounds__(256) void k_final(
    const float* __restrict__ Mbuf,
    const float* __restrict__ kqv,
    const float* __restrict__ qmax,
    const float* __restrict__ qinv,
    const float* __restrict__ x,
    const float* __restrict__ be,
    float* __restrict__ out)
{
  const int n  = blockIdx.z;
  const int oy = blockIdx.y;
  const int lx = blockIdx.x;
  const int tid = threadIdx.x;
  const int tx = tid & 15, ty = tid >> 4;

  __shared__ __align__(16) float As2[32][68];
  __shared__ __align__(16) float Bs2[32][68];

  float acc[4][4] = {};
  const float* Mp = Mbuf + ((size_t)n * 512 + oy * 64) * 256;
  const float* Qp = kqv + ((size_t)n * 1024 + KC) * L + (size_t)lx * 64;
  const float* qm = qmax + (size_t)n * NH * L + (size_t)lx * 64;
  const float* qi = qinv + (size_t)n * NH * L + (size_t)lx * 64;

  for (int kt = 0; kt < 8; ++kt) {
    #pragma unroll
    for (int i = 0; i < 8; ++i) {
      int idx = tid + i * 256;
      int o = idx >> 5, c = idx & 31;
      As2[c][o] = Mp[(size_t)o * 256 + kt * 32 + c];
    }
    #pragma unroll
    for (int i = 0; i < 8; ++i) {
      int idx = tid + i * 256;
      int c = idx >> 6, l = idx & 63;
      float qv = Qp[(size_t)(kt * 32 + c) * L + l];
      Bs2[c][l] = __expf(qv - qm[(size_t)kt * L + l]) * qi[(size_t)kt * L + l];
    }
    __syncthreads();
    #pragma unroll
    for (int kk = 0; kk < 32; ++kk) {
      float4 a = *(const float4*)&As2[kk][ty * 4];
      float4 b = *(const float4*)&Bs2[kk][tx * 4];
      float av[4] = {a.x, a.y, a.z, a.w};
      float bv4[4] = {b.x, b.y, b.z, b.w};
      #pragma unroll
      for (int i = 0; i < 4; ++i)
        #pragma unroll
        for (int j = 0; j < 4; ++j)
          acc[i][j] += av[i] * bv4[j];
    }
    __syncthreads();
  }

  const float* xp = x + ((size_t)n * 512 + oy * 64) * L + (size_t)lx * 64;
  float* op = out + ((size_t)n * 512 + oy * 64) * L + (size_t)lx * 64;
  #pragma unroll
  for (int i = 0; i < 4; ++i) {
    int o = ty * 4 + i;
    float bo = be[oy * 64 + o];
    #pragma unroll
    for (int j = 0; j < 4; ++j) {
      int l = tx * 4 + j;
      op[(size_t)o * L + l] = xp[(size_t)o * L + l] + acc[i][j] + bo;
    }
  }
}

// ---------------------------------------------------------------------------
extern "C" void kernel_launch(void* const* d_in, const int* in_sizes, int n_in,
                              void* d_out, int out_size, void* d_ws, size_t ws_size,
                              hipStream_t stream)
{
  const float* x  = (const float*)d_in[0];
  const float* Wk = (const float*)d_in[1];
  const float* bk = (const float*)d_in[2];
  const float* Wq = (const float*)d_in[3];
  const float* bq = (const float*)d_in[4];
  const float* Wv = (const float*)d_in[5];
  const float* bv = (const float*)d_in[6];
  const float* We = (const float*)d_in[7];
  const float* be = (const float*)d_in[8];
  float* out = (float*)d_out;

  char* ws = (char*)d_ws;
  size_t off = 0;
  float*  kqv  = (float*)(ws + off);  off += (size_t)N_BATCH * 1024 * L * 4;     // 268.4 MB
  ushort* xT   = (ushort*)(ws + off); off += (size_t)N_BATCH * L * C_IN * 2;     // 67.1 MB
  ushort* Wb   = (ushort*)(ws + off); off += (size_t)1024 * C_IN * 2;            // 1 MB
  float*  bb   = (float*)(ws + off);  off += (size_t)1024 * 4;
  float*  kmax = (float*)(ws + off);  off += (size_t)N_BATCH * KC * 4;
  float*  kinv = (float*)(ws + off);  off += (size_t)N_BATCH * KC * 4;
  float*  qmax = (float*)(ws + off);  off += (size_t)N_BATCH * NH * L * 4;
  float*  qinv = (float*)(ws + off);  off += (size_t)N_BATCH * NH * L * 4;
  float*  ctxp = (float*)(ws + off);  off += (size_t)N_BATCH * NH * CTX_CHUNKS * HV * HK * 4;
  float*  Mbuf = (float*)(ws + off);  off += (size_t)N_BATCH * 512 * 256 * 4;

  k_prep_w<<<dim3(1024), 256, 0, stream>>>(Wk, bk, Wq, bq, Wv, bv, Wb, bb);
  k_prep_x<<<dim3(64, 8, N_BATCH), 256, 0, stream>>>(x, xT);
  k_qkv_mfma<<<dim3(32, 8, N_BATCH), 256, 0, stream>>>(Wb, xT, bb, kqv);
  k_kstats<<<dim3(KC, N_BATCH), 256, 0, stream>>>(kqv, kmax, kinv);
  k_qstats<<<dim3((N_BATCH * NH * L) / 256), 256, 0, stream>>>(kqv, qmax, qinv);
  k_ctx<<<dim3(CTX_CHUNKS, N_BATCH * NH), 256, 0, stream>>>(kqv, kmax, kinv, ctxp);
  k_m<<<dim3(NH, N_BATCH), 256, 0, stream>>>(ctxp, We, Mbuf);
  k_final<<<dim3(64, 8, N_BATCH), 256, 0, stream>>>(Mbuf, kqv, qmax, qinv, x, be, out);
}

// Round 3
// 369.072 us; speedup vs baseline: 3.9380x; 1.8965x over previous
//
#include <hip/hip_runtime.h>
#include <cstddef>
#include <cstdint>

#define N_BATCH 16
#define C_IN    512
#define L       4096
#define KC      256
#define VC      512
#define NH      8
#define HK      32   // KC/NH
#define HV      64   // VC/NH
#define CTX_CHUNKS 8
#define CHUNK_L (L / CTX_CHUNKS)  // 512

using f32x4 = __attribute__((ext_vector_type(4))) float;
using s16x8 = __attribute__((ext_vector_type(8))) short;

// round-to-nearest-even fp32 -> bf16 bits
static __device__ inline ushort f2bf(float f) {
  uint32_t u = __float_as_uint(f);
  uint32_t r = (u + 0x7FFFu + ((u >> 16) & 1u)) >> 16;
  return (ushort)r;
}
static __device__ inline float bf2f(ushort u) {
  return __uint_as_float((uint32_t)u << 16);
}

// ---------------------------------------------------------------------------
// Prep 1: combined bf16 weight matrix Wb[1024][512] + combined bias bb[1024]
// rows 0..255 K, 256..511 Q, 512..1023 V
// ---------------------------------------------------------------------------
__global__ __launch_bounds__(256) void k_prep_w(
    const float* __restrict__ Wk, const float* __restrict__ bk,
    const float* __restrict__ Wq, const float* __restrict__ bq,
    const float* __restrict__ Wv, const float* __restrict__ bv,
    ushort* __restrict__ Wb, float* __restrict__ bb)
{
  const int o = blockIdx.x;          // 1024
  const float* src; const float* bsrc; int oo;
  if (o < 256)      { src = Wk + (size_t)o * C_IN;         bsrc = bk; oo = o; }
  else if (o < 512) { src = Wq + (size_t)(o - 256) * C_IN; bsrc = bq; oo = o - 256; }
  else              { src = Wv + (size_t)(o - 512) * C_IN; bsrc = bv; oo = o - 512; }
  const int t = threadIdx.x;
  Wb[(size_t)o * C_IN + t * 2]     = f2bf(src[t * 2]);
  Wb[(size_t)o * C_IN + t * 2 + 1] = f2bf(src[t * 2 + 1]);
  if (t == 0) bb[o] = bsrc[oo];
}

// ---------------------------------------------------------------------------
// Prep 2: transpose+cast x (n,512,4096) f32 -> xT (n,4096,512) bf16
// ---------------------------------------------------------------------------
__global__ __launch_bounds__(256) void k_prep_x(const float* __restrict__ x,
                                                ushort* __restrict__ xT)
{
  __shared__ float t[64][65];
  const int n = blockIdx.z, cy = blockIdx.y, lx = blockIdx.x;
  const float* xp = x + ((size_t)n * C_IN + cy * 64) * L + (size_t)lx * 64;
  const int ll = threadIdx.x & 63, c0 = threadIdx.x >> 6;
  #pragma unroll
  for (int i = 0; i < 16; ++i) {
    int cc = c0 + i * 4;
    t[cc][ll] = xp[(size_t)cc * L + ll];
  }
  __syncthreads();
  ushort* op = xT + ((size_t)n * L + lx * 64) * C_IN + cy * 64;
  const int cp = (threadIdx.x & 31) * 2, l0 = threadIdx.x >> 5;
  #pragma unroll
  for (int i = 0; i < 8; ++i) {
    int lr = l0 + i * 8;
    uint32_t pack = (uint32_t)f2bf(t[cp][lr]) | ((uint32_t)f2bf(t[cp + 1][lr]) << 16);
    *(uint32_t*)(op + (size_t)lr * C_IN + cp) = pack;
  }
}

// ---------------------------------------------------------------------------
// Kernel 1: KQV = Wb @ x + bias via bf16 MFMA -> kqv bf16 (n,1024,4096)
// 128x128 tile, BK=32, 4 waves (2x2), each wave 64x64 = 4x4 frags 16x16x32.
// ---------------------------------------------------------------------------
#define BM 128
#define BN 128
#define BK 32

__global__ __launch_bounds__(256) void k_qkv_mfma(
    const ushort* __restrict__ Wb,   // [1024][512] bf16
    const ushort* __restrict__ xT,   // [n][4096][512] bf16
    const float* __restrict__ bb,    // [1024]
    ushort* __restrict__ kqv)        // [n][1024][4096] bf16
{
  const int n  = blockIdx.z;
  const int oy = blockIdx.y;   // 8 row tiles
  const int lx = blockIdx.x;   // 32 col tiles
  const int tid  = threadIdx.x;
  const int wave = tid >> 6, lane = tid & 63;
  const int wr = wave >> 1, wc = wave & 1;

  __shared__ __align__(16) ushort As[BM * BK];
  __shared__ __align__(16) ushort Bs[BN * BK];

  f32x4 acc[4][4] = {};

  const ushort* gA = Wb + (size_t)(oy * BM) * C_IN;
  const ushort* gB = xT + ((size_t)n * L + lx * BN) * C_IN;

  const int r0 = wave * 32;
  const int lrow = lane >> 2;
  const int c8   = (lane & 3) * 8;

  for (int k0 = 0; k0 < C_IN; k0 += BK) {
    #pragma unroll
    for (int i = 0; i < 2; ++i) {
      int row = r0 + i * 16 + lrow;
      __builtin_amdgcn_global_load_lds(
          (const __attribute__((address_space(1))) uint32_t*)(gA + (size_t)row * C_IN + k0 + c8),
          (__attribute__((address_space(3))) uint32_t*)(As + (r0 + i * 16) * BK),
          16, 0, 0);
      __builtin_amdgcn_global_load_lds(
          (const __attribute__((address_space(1))) uint32_t*)(gB + (size_t)row * C_IN + k0 + c8),
          (__attribute__((address_space(3))) uint32_t*)(Bs + (r0 + i * 16) * BK),
          16, 0, 0);
    }
    __syncthreads();

    s16x8 af[4], bfr[4];
    #pragma unroll
    for (int m = 0; m < 4; ++m)
      af[m] = *(const s16x8*)&As[(wr * 64 + m * 16 + (lane & 15)) * BK + (lane >> 4) * 8];
    #pragma unroll
    for (int nn = 0; nn < 4; ++nn)
      bfr[nn] = *(const s16x8*)&Bs[(wc * 64 + nn * 16 + (lane & 15)) * BK + (lane >> 4) * 8];
    #pragma unroll
    for (int m = 0; m < 4; ++m)
      #pragma unroll
      for (int nn = 0; nn < 4; ++nn)
        acc[m][nn] = __builtin_amdgcn_mfma_f32_16x16x32_bf16(af[m], bfr[nn], acc[m][nn], 0, 0, 0);
    __syncthreads();
  }

  ushort* outp = kqv + ((size_t)n * 1024 + oy * BM) * L + (size_t)lx * BN;
  #pragma unroll
  for (int m = 0; m < 4; ++m) {
    int oo = wr * 64 + m * 16 + (lane >> 4) * 4;
    #pragma unroll
    for (int nn = 0; nn < 4; ++nn) {
      int ll = wc * 64 + nn * 16 + (lane & 15);
      f32x4 v = acc[m][nn];
      #pragma unroll
      for (int r = 0; r < 4; ++r) {
        int o = oo + r;
        outp[(size_t)o * L + ll] = f2bf(v[r] + bb[oy * BM + o]);
      }
    }
  }
}

// ---------------------------------------------------------------------------
// Reductions
// ---------------------------------------------------------------------------
__device__ inline float blockReduceMax(float v, float* red) {
  #pragma unroll
  for (int off = 32; off > 0; off >>= 1)
    v = fmaxf(v, __shfl_down(v, off, 64));
  int tid = threadIdx.x;
  if ((tid & 63) == 0) red[tid >> 6] = v;
  __syncthreads();
  return fmaxf(fmaxf(red[0], red[1]), fmaxf(red[2], red[3]));
}
__device__ inline float blockReduceSum(float v, float* red) {
  #pragma unroll
  for (int off = 32; off > 0; off >>= 1)
    v += __shfl_down(v, off, 64);
  int tid = threadIdx.x;
  if ((tid & 63) == 0) red[tid >> 6] = v;
  __syncthreads();
  return red[0] + red[1] + red[2] + red[3];
}

// ---------------------------------------------------------------------------
// Kernel 2: K softmax stats over L per (n, row) from bf16 K
// ---------------------------------------------------------------------------
__global__ __launch_bounds__(256) void k_kstats(const ushort* __restrict__ kqv,
                                                float* __restrict__ kmax,
                                                float* __restrict__ kinv)
{
  const int r = blockIdx.x;
  const int n = blockIdx.y;
  const ushort* row = kqv + ((size_t)n * 1024 + r) * L;
  __shared__ float red1[4];
  __shared__ float red2[4];
  const int tid = threadIdx.x;
  // each thread: 16 contiguous elems (2 x ushort8), lanes consecutive 32B
  s16x8 a = *(const s16x8*)(row + tid * 16);
  s16x8 b = *(const s16x8*)(row + tid * 16 + 8);
  float v[16];
  #pragma unroll
  for (int j = 0; j < 8; ++j) { v[j] = bf2f((ushort)a[j]); v[8 + j] = bf2f((ushort)b[j]); }
  float m = -3.0e38f;
  #pragma unroll
  for (int j = 0; j < 16; ++j) m = fmaxf(m, v[j]);
  m = blockReduceMax(m, red1);
  float s = 0.f;
  #pragma unroll
  for (int j = 0; j < 16; ++j) s += __expf(v[j] - m);
  s = blockReduceSum(s, red2);
  if (tid == 0) { kmax[n * KC + r] = m; kinv[n * KC + r] = 1.0f / s; }
}

// ---------------------------------------------------------------------------
// Kernel 3: Q channel-softmax + transpose: qT[n][l][256] bf16 normalized.
// grid (L/256, NH, n); thread owns one l for one head (32 values).
// ---------------------------------------------------------------------------
__global__ __launch_bounds__(256) void k_qT(const ushort* __restrict__ kqv,
                                            ushort* __restrict__ qT)
{
  const int n = blockIdx.z;
  const int h = blockIdx.y;
  const int l = blockIdx.x * 256 + threadIdx.x;
  const ushort* Qb = kqv + ((size_t)n * 1024 + KC + h * HK) * L + l;
  float p[HK];
  float m = -3.0e38f;
  #pragma unroll
  for (int k = 0; k < HK; ++k) {
    float v = bf2f(Qb[(size_t)k * L]);
    p[k] = v;
    m = fmaxf(m, v);
  }
  float s = 0.f;
  #pragma unroll
  for (int k = 0; k < HK; ++k) { p[k] = __expf(p[k] - m); s += p[k]; }
  float inv = 1.0f / s;
  ushort* dst = qT + ((size_t)n * L + l) * KC + h * HK;
  #pragma unroll
  for (int oct = 0; oct < 4; ++oct) {
    s16x8 w;
    #pragma unroll
    for (int j = 0; j < 8; ++j) w[j] = (short)f2bf(p[oct * 8 + j] * inv);
    *(s16x8*)(dst + oct * 8) = w;
  }
}

// ---------------------------------------------------------------------------
// Kernel 4: context partials via MFMA over l:
// ctx[v][k] = sum_l V[v,l] * K_sm[k,l].  grid (8 lchunks, 128 nh).
// Wave w owns v-rows [16w,16w+16); acc over the whole 512-l chunk.
// ---------------------------------------------------------------------------
__global__ __launch_bounds__(256) void k_ctx_mfma(const ushort* __restrict__ kqv,
                                                  const float* __restrict__ kmax,
                                                  const float* __restrict__ kinv,
                                                  float* __restrict__ ctxpart)
{
  const int chunk = blockIdx.x;   // 8
  const int nh    = blockIdx.y;   // 128
  const int n = nh >> 3, h = nh & 7;
  const int tid = threadIdx.x, wave = tid >> 6, lane = tid & 63;

  __shared__ __align__(16) ushort Ks[32 * 64];
  __shared__ __align__(16) ushort Vs[64 * 64];
  __shared__ float km[32], kv[32];

  if (tid < 32) { km[tid] = kmax[nh * 32 + tid]; kv[tid] = kinv[nh * 32 + tid]; }
  __syncthreads();

  const ushort* Kp = kqv + ((size_t)n * 1024 + h * HK) * L + (size_t)chunk * CHUNK_L;
  const ushort* Vp = kqv + ((size_t)n * 1024 + 512 + h * HV) * L + (size_t)chunk * CHUNK_L;

  const int krow = tid >> 3, kc = (tid & 7) * 8;
  f32x4 acc[2] = {};

  for (int step = 0; step < 8; ++step) {
    const int l0 = step * 64;
    // V tile 64x64 via global_load_lds (linear dest, 16B/lane)
    #pragma unroll
    for (int j = 0; j < 2; ++j) {
      int idx = (j * 4 + wave) * 64 + lane;
      int vr = idx >> 3, vc = (idx & 7) * 8;
      __builtin_amdgcn_global_load_lds(
          (const __attribute__((address_space(1))) uint32_t*)(Vp + (size_t)vr * L + l0 + vc),
          (__attribute__((address_space(3))) uint32_t*)(Vs + (size_t)(j * 4 + wave) * 512),
          16, 0, 0);
    }
    // K tile 32x64: load, softmax-normalize, pack bf16, LDS store
    s16x8 kvec = *(const s16x8*)(Kp + (size_t)krow * L + l0 + kc);
    float mk = km[krow], ik = kv[krow];
    s16x8 w;
    #pragma unroll
    for (int j = 0; j < 8; ++j) {
      float f = bf2f((ushort)kvec[j]);
      w[j] = (short)f2bf(__expf(f - mk) * ik);
    }
    *(s16x8*)&Ks[tid * 8] = w;
    __syncthreads();

    #pragma unroll
    for (int ks = 0; ks < 2; ++ks) {
      s16x8 af = *(const s16x8*)&Vs[(wave * 16 + (lane & 15)) * 64 + ks * 32 + (lane >> 4) * 8];
      #pragma unroll
      for (int nf = 0; nf < 2; ++nf) {
        s16x8 bfr = *(const s16x8*)&Ks[(nf * 16 + (lane & 15)) * 64 + ks * 32 + (lane >> 4) * 8];
        acc[nf] = __builtin_amdgcn_mfma_f32_16x16x32_bf16(af, bfr, acc[nf], 0, 0, 0);
      }
    }
    __syncthreads();
  }

  float* outp = ctxpart + ((size_t)nh * CTX_CHUNKS + chunk) * (HV * HK);
  #pragma unroll
  for (int nf = 0; nf < 2; ++nf) {
    #pragma unroll
    for (int r = 0; r < 4; ++r) {
      int v = wave * 16 + (lane >> 4) * 4 + r;
      int k = nf * 16 + (lane & 15);
      outp[v * HK + k] = acc[nf][r];
    }
  }
}

// ---------------------------------------------------------------------------
// Kernel 5: reduce ctx partials; fold We; write bf16 Mbuf [n][512][256]
// ---------------------------------------------------------------------------
__global__ __launch_bounds__(256) void k_m(const float* __restrict__ ctxpart,
                                           const float* __restrict__ We,
                                           ushort* __restrict__ Mbuf)
{
  const int h = blockIdx.x;
  const int n = blockIdx.y;
  const int nh = n * 8 + h;
  const int tid = threadIdx.x;
  __shared__ float ctx[64][32];

  #pragma unroll
  for (int i = 0; i < 8; ++i) {
    int e = tid + i * 256;
    float s = 0.f;
    for (int c = 0; c < CTX_CHUNKS; ++c)
      s += ctxpart[((size_t)nh * CTX_CHUNKS + c) * (HV * HK) + e];
    ((float*)ctx)[e] = s;
  }
  __syncthreads();

  const int k  = tid & 31;
  const int og = tid >> 5;
  for (int j = 0; j < 64; ++j) {
    int o = og * 64 + j;
    const float* we = We + (size_t)o * VC + h * HV;
    float s = 0.f;
    #pragma unroll
    for (int v = 0; v < 64; ++v) s += we[v] * ctx[v][k];
    Mbuf[((size_t)n * 512 + o) * KC + h * HK + k] = f2bf(s);
  }
}

// ---------------------------------------------------------------------------
// Kernel 6: out = x + be + M @ q_smT via MFMA.  M=512, N=4096(l), K=256.
// Same structure as k_qkv_mfma; grid (32 lx, 4 oy, 16 n).
// ---------------------------------------------------------------------------
__global__ __launch_bounds__(256) void k_final_mfma(
    const ushort* __restrict__ Mb,   // [n][512][256] bf16
    const ushort* __restrict__ qT,   // [n][4096][256] bf16
    const float* __restrict__ x,
    const float* __restrict__ be,
    float* __restrict__ out)
{
  const int n  = blockIdx.z;
  const int oy = blockIdx.y;   // 4
  const int lx = blockIdx.x;   // 32
  const int tid  = threadIdx.x;
  const int wave = tid >> 6, lane = tid & 63;
  const int wr = wave >> 1, wc = wave & 1;

  __shared__ __align__(16) ushort As[BM * BK];
  __shared__ __align__(16) ushort Bs[BN * BK];

  f32x4 acc[4][4] = {};

  const ushort* gA = Mb + ((size_t)n * 512 + oy * BM) * KC;
  const ushort* gB = qT + ((size_t)n * L + lx * BN) * KC;

  const int r0 = wave * 32;
  const int lrow = lane >> 2;
  const int c8   = (lane & 3) * 8;

  for (int k0 = 0; k0 < KC; k0 += BK) {
    #pragma unroll
    for (int i = 0; i < 2; ++i) {
      int row = r0 + i * 16 + lrow;
      __builtin_amdgcn_global_load_lds(
          (const __attribute__((address_space(1))) uint32_t*)(gA + (size_t)row * KC + k0 + c8),
          (__attribute__((address_space(3))) uint32_t*)(As + (r0 + i * 16) * BK),
          16, 0, 0);
      __builtin_amdgcn_global_load_lds(
          (const __attribute__((address_space(1))) uint32_t*)(gB + (size_t)row * KC + k0 + c8),
          (__attribute__((address_space(3))) uint32_t*)(Bs + (r0 + i * 16) * BK),
          16, 0, 0);
    }
    __syncthreads();

    s16x8 af[4], bfr[4];
    #pragma unroll
    for (int m = 0; m < 4; ++m)
      af[m] = *(const s16x8*)&As[(wr * 64 + m * 16 + (lane & 15)) * BK + (lane >> 4) * 8];
    #pragma unroll
    for (int nn = 0; nn < 4; ++nn)
      bfr[nn] = *(const s16x8*)&Bs[(wc * 64 + nn * 16 + (lane & 15)) * BK + (lane >> 4) * 8];
    #pragma unroll
    for (int m = 0; m < 4; ++m)
      #pragma unroll
      for (int nn = 0; nn < 4; ++nn)
        acc[m][nn] = __builtin_amdgcn_mfma_f32_16x16x32_bf16(af[m], bfr[nn], acc[m][nn], 0, 0, 0);
    __syncthreads();
  }

  const float* xp = x + ((size_t)n * 512 + oy * BM) * L + (size_t)lx * BN;
  float* op = out + ((size_t)n * 512 + oy * BM) * L + (size_t)lx * BN;
  #pragma unroll
  for (int m = 0; m < 4; ++m) {
    int oo = wr * 64 + m * 16 + (lane >> 4) * 4;
    #pragma unroll
    for (int nn = 0; nn < 4; ++nn) {
      int ll = wc * 64 + nn * 16 + (lane & 15);
      f32x4 v = acc[m][nn];
      #pragma unroll
      for (int r = 0; r < 4; ++r) {
        int o = oo + r;
        op[(size_t)o * L + ll] = v[r] + xp[(size_t)o * L + ll] + be[oy * BM + o];
      }
    }
  }
}

// ---------------------------------------------------------------------------
extern "C" void kernel_launch(void* const* d_in, const int* in_sizes, int n_in,
                              void* d_out, int out_size, void* d_ws, size_t ws_size,
                              hipStream_t stream)
{
  const float* x  = (const float*)d_in[0];
  const float* Wk = (const float*)d_in[1];
  const float* bk = (const float*)d_in[2];
  const float* Wq = (const float*)d_in[3];
  const float* bq = (const float*)d_in[4];
  const float* Wv = (const float*)d_in[5];
  const float* bv = (const float*)d_in[6];
  const float* We = (const float*)d_in[7];
  const float* be = (const float*)d_in[8];
  float* out = (float*)d_out;

  char* ws = (char*)d_ws;
  size_t off = 0;
  ushort* kqv  = (ushort*)(ws + off); off += (size_t)N_BATCH * 1024 * L * 2;     // 134.2 MB
  ushort* xT   = (ushort*)(ws + off); off += (size_t)N_BATCH * L * C_IN * 2;     // 67.1 MB
  ushort* Wb   = (ushort*)(ws + off); off += (size_t)1024 * C_IN * 2;            // 1 MB
  float*  bb   = (float*)(ws + off);  off += (size_t)1024 * 4;
  float*  kmax = (float*)(ws + off);  off += (size_t)N_BATCH * KC * 4;
  float*  kinv = (float*)(ws + off);  off += (size_t)N_BATCH * KC * 4;
  ushort* qT   = (ushort*)(ws + off); off += (size_t)N_BATCH * L * KC * 2;       // 33.6 MB
  float*  ctxp = (float*)(ws + off);  off += (size_t)N_BATCH * NH * CTX_CHUNKS * HV * HK * 4;
  ushort* Mbuf = (ushort*)(ws + off); off += (size_t)N_BATCH * 512 * KC * 2;

  k_prep_w<<<dim3(1024), 256, 0, stream>>>(Wk, bk, Wq, bq, Wv, bv, Wb, bb);
  k_prep_x<<<dim3(64, 8, N_BATCH), 256, 0, stream>>>(x, xT);
  k_qkv_mfma<<<dim3(32, 8, N_BATCH), 256, 0, stream>>>(Wb, xT, bb, kqv);
  k_kstats<<<dim3(KC, N_BATCH), 256, 0, stream>>>(kqv, kmax, kinv);
  k_qT<<<dim3(L / 256, NH, N_BATCH), 256, 0, stream>>>(kqv, qT);
  k_ctx_mfma<<<dim3(CTX_CHUNKS, N_BATCH * NH), 256, 0, stream>>>(kqv, kmax, kinv, ctxp);
  k_m<<<dim3(NH, N_BATCH), 256, 0, stream>>>(ctxp, We, Mbuf);
  k_final_mfma<<<dim3(32, 4, N_BATCH), 256, 0, stream>>>(Mbuf, qT, x, be, out);
}

// Round 4
// 330.204 us; speedup vs baseline: 4.4016x; 1.1177x over previous
//
#include <hip/hip_runtime.h>
#include <cstddef>
#include <cstdint>

#define N_BATCH 16
#define C_IN    512
#define L       4096
#define KC      256
#define VC      512
#define NH      8
#define HK      32   // KC/NH
#define HV      64   // VC/NH
#define CTX_CHUNKS 8
#define CHUNK_L (L / CTX_CHUNKS)  // 512

using f32x4 = __attribute__((ext_vector_type(4))) float;
using s16x8 = __attribute__((ext_vector_type(8))) short;

// round-to-nearest-even fp32 -> bf16 bits
static __device__ inline ushort f2bf(float f) {
  uint32_t u = __float_as_uint(f);
  uint32_t r = (u + 0x7FFFu + ((u >> 16) & 1u)) >> 16;
  return (ushort)r;
}
static __device__ inline float bf2f(ushort u) {
  return __uint_as_float((uint32_t)u << 16);
}

// ---------------------------------------------------------------------------
// Prep 1: combined bf16 weight matrix Wb[1024][512] + combined bias bb[1024]
// ---------------------------------------------------------------------------
__global__ __launch_bounds__(256) void k_prep_w(
    const float* __restrict__ Wk, const float* __restrict__ bk,
    const float* __restrict__ Wq, const float* __restrict__ bq,
    const float* __restrict__ Wv, const float* __restrict__ bv,
    ushort* __restrict__ Wb, float* __restrict__ bb)
{
  const int o = blockIdx.x;          // 1024
  const float* src; const float* bsrc; int oo;
  if (o < 256)      { src = Wk + (size_t)o * C_IN;         bsrc = bk; oo = o; }
  else if (o < 512) { src = Wq + (size_t)(o - 256) * C_IN; bsrc = bq; oo = o - 256; }
  else              { src = Wv + (size_t)(o - 512) * C_IN; bsrc = bv; oo = o - 512; }
  const int t = threadIdx.x;
  Wb[(size_t)o * C_IN + t * 2]     = f2bf(src[t * 2]);
  Wb[(size_t)o * C_IN + t * 2 + 1] = f2bf(src[t * 2 + 1]);
  if (t == 0) bb[o] = bsrc[oo];
}

// ---------------------------------------------------------------------------
// Prep 2: transpose+cast x (n,512,4096) f32 -> xT (n,4096,512) bf16
// float4 global loads; [64][65] LDS (2-way conflicts only).
// ---------------------------------------------------------------------------
__global__ __launch_bounds__(256) void k_prep_x(const float* __restrict__ x,
                                                ushort* __restrict__ xT)
{
  __shared__ float t[64][65];
  const int n = blockIdx.z, cy = blockIdx.y, lx = blockIdx.x;
  const float* xp = x + ((size_t)n * C_IN + cy * 64) * L + (size_t)lx * 64;
  const int l4 = (threadIdx.x & 15) * 4;
  const int c0 = threadIdx.x >> 4;       // 0..15
  #pragma unroll
  for (int i = 0; i < 4; ++i) {
    int cc = c0 + i * 16;
    f32x4 v = *(const f32x4*)&xp[(size_t)cc * L + l4];
    t[cc][l4]     = v[0];
    t[cc][l4 + 1] = v[1];
    t[cc][l4 + 2] = v[2];
    t[cc][l4 + 3] = v[3];
  }
  __syncthreads();
  ushort* op = xT + ((size_t)n * L + lx * 64) * C_IN + cy * 64;
  const int cp = (threadIdx.x & 31) * 2, l0 = threadIdx.x >> 5;
  #pragma unroll
  for (int i = 0; i < 8; ++i) {
    int lr = l0 + i * 8;
    uint32_t pack = (uint32_t)f2bf(t[cp][lr]) | ((uint32_t)f2bf(t[cp + 1][lr]) << 16);
    *(uint32_t*)(op + (size_t)lr * C_IN + cp) = pack;
  }
}

// ---------------------------------------------------------------------------
// Kernel 1: KQV = Wb @ x + bias via bf16 MFMA -> kqv bf16 (n,1024,4096)
// 128x128 tile, BK=32, 4 waves (2x2). Vectorized epilogue via per-wave LDS
// transpose (16x68 f32, overlaid on As/Bs after final barrier).
// ---------------------------------------------------------------------------
#define BM 128
#define BN 128
#define BK 32

__global__ __launch_bounds__(256) void k_qkv_mfma(
    const ushort* __restrict__ Wb,   // [1024][512] bf16
    const ushort* __restrict__ xT,   // [n][4096][512] bf16
    const float* __restrict__ bb,    // [1024]
    ushort* __restrict__ kqv)        // [n][1024][4096] bf16
{
  const int n  = blockIdx.z;
  const int oy = blockIdx.y;   // 8 row tiles
  const int lx = blockIdx.x;   // 32 col tiles
  const int tid  = threadIdx.x;
  const int wave = tid >> 6, lane = tid & 63;
  const int wr = wave >> 1, wc = wave & 1;

  __shared__ __align__(16) char smem[17408];
  ushort* As = (ushort*)smem;            // 8192 B
  ushort* Bs = (ushort*)(smem + 8192);   // 8192 B

  f32x4 acc[4][4] = {};

  const ushort* gA = Wb + (size_t)(oy * BM) * C_IN;
  const ushort* gB = xT + ((size_t)n * L + lx * BN) * C_IN;

  const int r0 = wave * 32;
  const int lrow = lane >> 2;
  const int c8   = (lane & 3) * 8;

  for (int k0 = 0; k0 < C_IN; k0 += BK) {
    #pragma unroll
    for (int i = 0; i < 2; ++i) {
      int row = r0 + i * 16 + lrow;
      __builtin_amdgcn_global_load_lds(
          (const __attribute__((address_space(1))) uint32_t*)(gA + (size_t)row * C_IN + k0 + c8),
          (__attribute__((address_space(3))) uint32_t*)(As + (r0 + i * 16) * BK),
          16, 0, 0);
      __builtin_amdgcn_global_load_lds(
          (const __attribute__((address_space(1))) uint32_t*)(gB + (size_t)row * C_IN + k0 + c8),
          (__attribute__((address_space(3))) uint32_t*)(Bs + (r0 + i * 16) * BK),
          16, 0, 0);
    }
    __syncthreads();

    s16x8 af[4], bfr[4];
    #pragma unroll
    for (int m = 0; m < 4; ++m)
      af[m] = *(const s16x8*)&As[(wr * 64 + m * 16 + (lane & 15)) * BK + (lane >> 4) * 8];
    #pragma unroll
    for (int nn = 0; nn < 4; ++nn)
      bfr[nn] = *(const s16x8*)&Bs[(wc * 64 + nn * 16 + (lane & 15)) * BK + (lane >> 4) * 8];
    #pragma unroll
    for (int m = 0; m < 4; ++m)
      #pragma unroll
      for (int nn = 0; nn < 4; ++nn)
        acc[m][nn] = __builtin_amdgcn_mfma_f32_16x16x32_bf16(af[m], bfr[nn], acc[m][nn], 0, 0, 0);
    __syncthreads();
  }

  // Epilogue: wave-private 16x68 f32 staging -> packed bf16 uint2 stores.
  float* ep = (float*)smem + wave * (16 * 68);
  const int erow = lane >> 4;   // 0..3
  const int ecol = lane & 15;
  const float* bias = bb + oy * BM + wr * 64;
  ushort* outp = kqv + ((size_t)n * 1024 + oy * BM + wr * 64) * L
               + (size_t)lx * BN + wc * 64;
  #pragma unroll
  for (int m = 0; m < 4; ++m) {
    #pragma unroll
    for (int nn = 0; nn < 4; ++nn)
      #pragma unroll
      for (int r = 0; r < 4; ++r)
        ep[(erow * 4 + r) * 68 + nn * 16 + ecol] = acc[m][nn][r];
    #pragma unroll
    for (int p = 0; p < 4; ++p) {
      int row = p * 4 + erow;                 // 0..15
      f32x4 v = *(const f32x4*)&ep[row * 68 + ecol * 4];
      float bo = bias[m * 16 + row];
      uint2 pk;
      pk.x = (uint32_t)f2bf(v[0] + bo) | ((uint32_t)f2bf(v[1] + bo) << 16);
      pk.y = (uint32_t)f2bf(v[2] + bo) | ((uint32_t)f2bf(v[3] + bo) << 16);
      *(uint2*)&outp[(size_t)(m * 16 + row) * L + ecol * 4] = pk;
    }
  }
}

// ---------------------------------------------------------------------------
// Reductions
// ---------------------------------------------------------------------------
__device__ inline float blockReduceMax(float v, float* red) {
  #pragma unroll
  for (int off = 32; off > 0; off >>= 1)
    v = fmaxf(v, __shfl_down(v, off, 64));
  int tid = threadIdx.x;
  if ((tid & 63) == 0) red[tid >> 6] = v;
  __syncthreads();
  return fmaxf(fmaxf(red[0], red[1]), fmaxf(red[2], red[3]));
}
__device__ inline float blockReduceSum(float v, float* red) {
  #pragma unroll
  for (int off = 32; off > 0; off >>= 1)
    v += __shfl_down(v, off, 64);
  int tid = threadIdx.x;
  if ((tid & 63) == 0) red[tid >> 6] = v;
  __syncthreads();
  return red[0] + red[1] + red[2] + red[3];
}

// ---------------------------------------------------------------------------
// Kernel 2: K softmax stats over L per (n, row) from bf16 K
// ---------------------------------------------------------------------------
__global__ __launch_bounds__(256) void k_kstats(const ushort* __restrict__ kqv,
                                                float* __restrict__ kmax,
                                                float* __restrict__ kinv)
{
  const int r = blockIdx.x;
  const int n = blockIdx.y;
  const ushort* row = kqv + ((size_t)n * 1024 + r) * L;
  __shared__ float red1[4];
  __shared__ float red2[4];
  const int tid = threadIdx.x;
  s16x8 a = *(const s16x8*)(row + tid * 16);
  s16x8 b = *(const s16x8*)(row + tid * 16 + 8);
  float v[16];
  #pragma unroll
  for (int j = 0; j < 8; ++j) { v[j] = bf2f((ushort)a[j]); v[8 + j] = bf2f((ushort)b[j]); }
  float m = -3.0e38f;
  #pragma unroll
  for (int j = 0; j < 16; ++j) m = fmaxf(m, v[j]);
  m = blockReduceMax(m, red1);
  float s = 0.f;
  #pragma unroll
  for (int j = 0; j < 16; ++j) s += __expf(v[j] - m);
  s = blockReduceSum(s, red2);
  if (tid == 0) { kmax[n * KC + r] = m; kinv[n * KC + r] = 1.0f / s; }
}

// ---------------------------------------------------------------------------
// Kernel 3: Q channel-softmax + transpose: qT[n][l][256] bf16 normalized.
// ---------------------------------------------------------------------------
__global__ __launch_bounds__(256) void k_qT(const ushort* __restrict__ kqv,
                                            ushort* __restrict__ qT)
{
  const int n = blockIdx.z;
  const int h = blockIdx.y;
  const int l = blockIdx.x * 256 + threadIdx.x;
  const ushort* Qb = kqv + ((size_t)n * 1024 + KC + h * HK) * L + l;
  float p[HK];
  float m = -3.0e38f;
  #pragma unroll
  for (int k = 0; k < HK; ++k) {
    float v = bf2f(Qb[(size_t)k * L]);
    p[k] = v;
    m = fmaxf(m, v);
  }
  float s = 0.f;
  #pragma unroll
  for (int k = 0; k < HK; ++k) { p[k] = __expf(p[k] - m); s += p[k]; }
  float inv = 1.0f / s;
  ushort* dst = qT + ((size_t)n * L + l) * KC + h * HK;
  #pragma unroll
  for (int oct = 0; oct < 4; ++oct) {
    s16x8 w;
    #pragma unroll
    for (int j = 0; j < 8; ++j) w[j] = (short)f2bf(p[oct * 8 + j] * inv);
    *(s16x8*)(dst + oct * 8) = w;
  }
}

// ---------------------------------------------------------------------------
// Kernel 4: context partials via MFMA over l
// ---------------------------------------------------------------------------
__global__ __launch_bounds__(256) void k_ctx_mfma(const ushort* __restrict__ kqv,
                                                  const float* __restrict__ kmax,
                                                  const float* __restrict__ kinv,
                                                  float* __restrict__ ctxpart)
{
  const int chunk = blockIdx.x;   // 8
  const int nh    = blockIdx.y;   // 128
  const int n = nh >> 3, h = nh & 7;
  const int tid = threadIdx.x, wave = tid >> 6, lane = tid & 63;

  __shared__ __align__(16) ushort Ks[32 * 64];
  __shared__ __align__(16) ushort Vs[64 * 64];
  __shared__ float km[32], kv[32];

  if (tid < 32) { km[tid] = kmax[nh * 32 + tid]; kv[tid] = kinv[nh * 32 + tid]; }
  __syncthreads();

  const ushort* Kp = kqv + ((size_t)n * 1024 + h * HK) * L + (size_t)chunk * CHUNK_L;
  const ushort* Vp = kqv + ((size_t)n * 1024 + 512 + h * HV) * L + (size_t)chunk * CHUNK_L;

  const int krow = tid >> 3, kc = (tid & 7) * 8;
  f32x4 acc[2] = {};

  for (int step = 0; step < 8; ++step) {
    const int l0 = step * 64;
    #pragma unroll
    for (int j = 0; j < 2; ++j) {
      int idx = (j * 4 + wave) * 64 + lane;
      int vr = idx >> 3, vc = (idx & 7) * 8;
      __builtin_amdgcn_global_load_lds(
          (const __attribute__((address_space(1))) uint32_t*)(Vp + (size_t)vr * L + l0 + vc),
          (__attribute__((address_space(3))) uint32_t*)(Vs + (size_t)(j * 4 + wave) * 512),
          16, 0, 0);
    }
    s16x8 kvec = *(const s16x8*)(Kp + (size_t)krow * L + l0 + kc);
    float mk = km[krow], ik = kv[krow];
    s16x8 w;
    #pragma unroll
    for (int j = 0; j < 8; ++j) {
      float f = bf2f((ushort)kvec[j]);
      w[j] = (short)f2bf(__expf(f - mk) * ik);
    }
    *(s16x8*)&Ks[tid * 8] = w;
    __syncthreads();

    #pragma unroll
    for (int ks = 0; ks < 2; ++ks) {
      s16x8 af = *(const s16x8*)&Vs[(wave * 16 + (lane & 15)) * 64 + ks * 32 + (lane >> 4) * 8];
      #pragma unroll
      for (int nf = 0; nf < 2; ++nf) {
        s16x8 bfr = *(const s16x8*)&Ks[(nf * 16 + (lane & 15)) * 64 + ks * 32 + (lane >> 4) * 8];
        acc[nf] = __builtin_amdgcn_mfma_f32_16x16x32_bf16(af, bfr, acc[nf], 0, 0, 0);
      }
    }
    __syncthreads();
  }

  float* outp = ctxpart + ((size_t)nh * CTX_CHUNKS + chunk) * (HV * HK);
  #pragma unroll
  for (int nf = 0; nf < 2; ++nf) {
    #pragma unroll
    for (int r = 0; r < 4; ++r) {
      int v = wave * 16 + (lane >> 4) * 4 + r;
      int k = nf * 16 + (lane & 15);
      outp[v * HK + k] = acc[nf][r];
    }
  }
}

// ---------------------------------------------------------------------------
// Kernel 5: reduce ctx partials; fold We; write bf16 Mbuf [n][512][256]
// ---------------------------------------------------------------------------
__global__ __launch_bounds__(256) void k_m(const float* __restrict__ ctxpart,
                                           const float* __restrict__ We,
                                           ushort* __restrict__ Mbuf)
{
  const int h = blockIdx.x;
  const int n = blockIdx.y;
  const int nh = n * 8 + h;
  const int tid = threadIdx.x;
  __shared__ float ctx[64][32];

  #pragma unroll
  for (int i = 0; i < 8; ++i) {
    int e = tid + i * 256;
    float s = 0.f;
    for (int c = 0; c < CTX_CHUNKS; ++c)
      s += ctxpart[((size_t)nh * CTX_CHUNKS + c) * (HV * HK) + e];
    ((float*)ctx)[e] = s;
  }
  __syncthreads();

  const int k  = tid & 31;
  const int og = tid >> 5;
  for (int j = 0; j < 64; ++j) {
    int o = og * 64 + j;
    const float* we = We + (size_t)o * VC + h * HV;
    float s = 0.f;
    #pragma unroll
    for (int v = 0; v < 64; ++v) s += we[v] * ctx[v][k];
    Mbuf[((size_t)n * 512 + o) * KC + h * HK + k] = f2bf(s);
  }
}

// ---------------------------------------------------------------------------
// Kernel 6: out = x + be + M @ q_smT via MFMA.  M=512, N=4096(l), K=256.
// Vectorized epilogue: LDS transpose -> float4 x-load + float4 store.
// ---------------------------------------------------------------------------
__global__ __launch_bounds__(256) void k_final_mfma(
    const ushort* __restrict__ Mb,   // [n][512][256] bf16
    const ushort* __restrict__ qT,   // [n][4096][256] bf16
    const float* __restrict__ x,
    const float* __restrict__ be,
    float* __restrict__ out)
{
  const int n  = blockIdx.z;
  const int oy = blockIdx.y;   // 4
  const int lx = blockIdx.x;   // 32
  const int tid  = threadIdx.x;
  const int wave = tid >> 6, lane = tid & 63;
  const int wr = wave >> 1, wc = wave & 1;

  __shared__ __align__(16) char smem[17408];
  ushort* As = (ushort*)smem;
  ushort* Bs = (ushort*)(smem + 8192);

  f32x4 acc[4][4] = {};

  const ushort* gA = Mb + ((size_t)n * 512 + oy * BM) * KC;
  const ushort* gB = qT + ((size_t)n * L + lx * BN) * KC;

  const int r0 = wave * 32;
  const int lrow = lane >> 2;
  const int c8   = (lane & 3) * 8;

  for (int k0 = 0; k0 < KC; k0 += BK) {
    #pragma unroll
    for (int i = 0; i < 2; ++i) {
      int row = r0 + i * 16 + lrow;
      __builtin_amdgcn_global_load_lds(
          (const __attribute__((address_space(1))) uint32_t*)(gA + (size_t)row * KC + k0 + c8),
          (__attribute__((address_space(3))) uint32_t*)(As + (r0 + i * 16) * BK),
          16, 0, 0);
      __builtin_amdgcn_global_load_lds(
          (const __attribute__((address_space(1))) uint32_t*)(gB + (size_t)row * KC + k0 + c8),
          (__attribute__((address_space(3))) uint32_t*)(Bs + (r0 + i * 16) * BK),
          16, 0, 0);
    }
    __syncthreads();

    s16x8 af[4], bfr[4];
    #pragma unroll
    for (int m = 0; m < 4; ++m)
      af[m] = *(const s16x8*)&As[(wr * 64 + m * 16 + (lane & 15)) * BK + (lane >> 4) * 8];
    #pragma unroll
    for (int nn = 0; nn < 4; ++nn)
      bfr[nn] = *(const s16x8*)&Bs[(wc * 64 + nn * 16 + (lane & 15)) * BK + (lane >> 4) * 8];
    #pragma unroll
    for (int m = 0; m < 4; ++m)
      #pragma unroll
      for (int nn = 0; nn < 4; ++nn)
        acc[m][nn] = __builtin_amdgcn_mfma_f32_16x16x32_bf16(af[m], bfr[nn], acc[m][nn], 0, 0, 0);
    __syncthreads();
  }

  // Epilogue: wave-private 16x68 f32 staging -> float4 x-add + float4 store.
  float* ep = (float*)smem + wave * (16 * 68);
  const int erow = lane >> 4;
  const int ecol = lane & 15;
  const float* bias = be + oy * BM + wr * 64;
  const float* xp = x + ((size_t)n * 512 + oy * BM + wr * 64) * L
                  + (size_t)lx * BN + wc * 64;
  float* op = out + ((size_t)n * 512 + oy * BM + wr * 64) * L
            + (size_t)lx * BN + wc * 64;
  #pragma unroll
  for (int m = 0; m < 4; ++m) {
    #pragma unroll
    for (int nn = 0; nn < 4; ++nn)
      #pragma unroll
      for (int r = 0; r < 4; ++r)
        ep[(erow * 4 + r) * 68 + nn * 16 + ecol] = acc[m][nn][r];
    #pragma unroll
    for (int p = 0; p < 4; ++p) {
      int row = p * 4 + erow;
      f32x4 v = *(const f32x4*)&ep[row * 68 + ecol * 4];
      float bo = bias[m * 16 + row];
      f32x4 xv = *(const f32x4*)&xp[(size_t)(m * 16 + row) * L + ecol * 4];
      v = v + xv + bo;
      *(f32x4*)&op[(size_t)(m * 16 + row) * L + ecol * 4] = v;
    }
  }
}

// ---------------------------------------------------------------------------
extern "C" void kernel_launch(void* const* d_in, const int* in_sizes, int n_in,
                              void* d_out, int out_size, void* d_ws, size_t ws_size,
                              hipStream_t stream)
{
  const float* x  = (const float*)d_in[0];
  const float* Wk = (const float*)d_in[1];
  const float* bk = (const float*)d_in[2];
  const float* Wq = (const float*)d_in[3];
  const float* bq = (const float*)d_in[4];
  const float* Wv = (const float*)d_in[5];
  const float* bv = (const float*)d_in[6];
  const float* We = (const float*)d_in[7];
  const float* be = (const float*)d_in[8];
  float* out = (float*)d_out;

  char* ws = (char*)d_ws;
  size_t off = 0;
  ushort* kqv  = (ushort*)(ws + off); off += (size_t)N_BATCH * 1024 * L * 2;
  ushort* xT   = (ushort*)(ws + off); off += (size_t)N_BATCH * L * C_IN * 2;
  ushort* Wb   = (ushort*)(ws + off); off += (size_t)1024 * C_IN * 2;
  float*  bb   = (float*)(ws + off);  off += (size_t)1024 * 4;
  float*  kmax = (float*)(ws + off);  off += (size_t)N_BATCH * KC * 4;
  float*  kinv = (float*)(ws + off);  off += (size_t)N_BATCH * KC * 4;
  ushort* qT   = (ushort*)(ws + off); off += (size_t)N_BATCH * L * KC * 2;
  float*  ctxp = (float*)(ws + off);  off += (size_t)N_BATCH * NH * CTX_CHUNKS * HV * HK * 4;
  ushort* Mbuf = (ushort*)(ws + off); off += (size_t)N_BATCH * 512 * KC * 2;

  k_prep_w<<<dim3(1024), 256, 0, stream>>>(Wk, bk, Wq, bq, Wv, bv, Wb, bb);
  k_prep_x<<<dim3(64, 8, N_BATCH), 256, 0, stream>>>(x, xT);
  k_qkv_mfma<<<dim3(32, 8, N_BATCH), 256, 0, stream>>>(Wb, xT, bb, kqv);
  k_kstats<<<dim3(KC, N_BATCH), 256, 0, stream>>>(kqv, kmax, kinv);
  k_qT<<<dim3(L / 256, NH, N_BATCH), 256, 0, stream>>>(kqv, qT);
  k_ctx_mfma<<<dim3(CTX_CHUNKS, N_BATCH * NH), 256, 0, stream>>>(kqv, kmax, kinv, ctxp);
  k_m<<<dim3(NH, N_BATCH), 256, 0, stream>>>(ctxp, We, Mbuf);
  k_final_mfma<<<dim3(32, 4, N_BATCH), 256, 0, stream>>>(Mbuf, qT, x, be, out);
}

// Round 5
// 302.737 us; speedup vs baseline: 4.8009x; 1.0907x over previous
//
#include <hip/hip_runtime.h>
#include <cstddef>
#include <cstdint>

#define N_BATCH 16
#define C_IN    512
#define L       4096
#define KC      256
#define VC      512
#define NH      8
#define HK      32   // KC/NH
#define HV      64   // VC/NH
#define CTX_CHUNKS 8
#define CHUNK_L (L / CTX_CHUNKS)  // 512

using f32x4 = __attribute__((ext_vector_type(4))) float;
using s16x8 = __attribute__((ext_vector_type(8))) short;

// round-to-nearest-even fp32 -> bf16 bits
static __device__ inline ushort f2bf(float f) {
  uint32_t u = __float_as_uint(f);
  uint32_t r = (u + 0x7FFFu + ((u >> 16) & 1u)) >> 16;
  return (ushort)r;
}
static __device__ inline float bf2f(ushort u) {
  return __uint_as_float((uint32_t)u << 16);
}

// ---------------------------------------------------------------------------
// Prep 1: combined bf16 weight matrix Wb[1024][512] + combined bias bb[1024]
// ---------------------------------------------------------------------------
__global__ __launch_bounds__(256) void k_prep_w(
    const float* __restrict__ Wk, const float* __restrict__ bk,
    const float* __restrict__ Wq, const float* __restrict__ bq,
    const float* __restrict__ Wv, const float* __restrict__ bv,
    ushort* __restrict__ Wb, float* __restrict__ bb)
{
  const int o = blockIdx.x;          // 1024
  const float* src; const float* bsrc; int oo;
  if (o < 256)      { src = Wk + (size_t)o * C_IN;         bsrc = bk; oo = o; }
  else if (o < 512) { src = Wq + (size_t)(o - 256) * C_IN; bsrc = bq; oo = o - 256; }
  else              { src = Wv + (size_t)(o - 512) * C_IN; bsrc = bv; oo = o - 512; }
  const int t = threadIdx.x;
  Wb[(size_t)o * C_IN + t * 2]     = f2bf(src[t * 2]);
  Wb[(size_t)o * C_IN + t * 2 + 1] = f2bf(src[t * 2 + 1]);
  if (t == 0) bb[o] = bsrc[oo];
}

// ---------------------------------------------------------------------------
// Prep 2: transpose+cast x (n,512,4096) f32 -> xT (n,4096,512) bf16
// ---------------------------------------------------------------------------
__global__ __launch_bounds__(256) void k_prep_x(const float* __restrict__ x,
                                                ushort* __restrict__ xT)
{
  __shared__ float t[64][65];
  const int n = blockIdx.z, cy = blockIdx.y, lx = blockIdx.x;
  const float* xp = x + ((size_t)n * C_IN + cy * 64) * L + (size_t)lx * 64;
  const int l4 = (threadIdx.x & 15) * 4;
  const int c0 = threadIdx.x >> 4;
  #pragma unroll
  for (int i = 0; i < 4; ++i) {
    int cc = c0 + i * 16;
    f32x4 v = *(const f32x4*)&xp[(size_t)cc * L + l4];
    t[cc][l4]     = v[0];
    t[cc][l4 + 1] = v[1];
    t[cc][l4 + 2] = v[2];
    t[cc][l4 + 3] = v[3];
  }
  __syncthreads();
  ushort* op = xT + ((size_t)n * L + lx * 64) * C_IN + cy * 64;
  const int cp = (threadIdx.x & 31) * 2, l0 = threadIdx.x >> 5;
  #pragma unroll
  for (int i = 0; i < 8; ++i) {
    int lr = l0 + i * 8;
    uint32_t pack = (uint32_t)f2bf(t[cp][lr]) | ((uint32_t)f2bf(t[cp + 1][lr]) << 16);
    *(uint32_t*)(op + (size_t)lr * C_IN + cp) = pack;
  }
}

// ---------------------------------------------------------------------------
// Kernel 1: KQV = Wb @ x + bias via bf16 MFMA -> kqv bf16 (n,1024,4096)
// 256x256 tile, BK=64, 8 waves (2Mx4N), single-buffer LDS, 2-barrier loop.
// LDS rows are 128B; XOR swizzle slot^=(row&7) applied as pre-swizzled
// global source (linear gload_lds dest) + swizzled ds_read slot.
// ---------------------------------------------------------------------------
#define QBM 256
#define QBN 256
#define QBK 64

__global__ __launch_bounds__(512) void k_qkv_mfma(
    const ushort* __restrict__ Wb,   // [1024][512] bf16
    const ushort* __restrict__ xT,   // [n][4096][512] bf16
    const float* __restrict__ bb,    // [1024]
    ushort* __restrict__ kqv)        // [n][1024][4096] bf16
{
  const int n  = blockIdx.z;
  const int oy = blockIdx.y;   // 4 row tiles of 256
  const int lx = blockIdx.x;   // 16 col tiles of 256
  const int tid  = threadIdx.x;
  const int wave = tid >> 6, lane = tid & 63;
  const int wr = wave >> 2, wc = wave & 3;   // 2 x 4

  __shared__ __align__(16) char smem[65536];
  ushort* As = (ushort*)smem;             // 256x64 bf16 = 32 KB
  ushort* Bs = (ushort*)(smem + 32768);   // 32 KB

  f32x4 acc[8][4] = {};

  const ushort* gA = Wb + (size_t)(oy * QBM) * C_IN;
  const ushort* gB = xT + ((size_t)n * L + lx * QBN) * C_IN;

  for (int k0 = 0; k0 < C_IN; k0 += QBK) {
    // stage: wave w covers rows [w*32, w*32+32) of both tiles.
    #pragma unroll
    for (int i = 0; i < 4; ++i) {
      int rbase = wave * 32 + i * 8;
      int row = rbase + (lane >> 3);
      int sslot = (lane & 7) ^ (row & 7);       // pre-swizzled source slot
      __builtin_amdgcn_global_load_lds(
          (const __attribute__((address_space(1))) uint32_t*)(gA + (size_t)row * C_IN + k0 + sslot * 8),
          (__attribute__((address_space(3))) uint32_t*)(As + rbase * QBK),
          16, 0, 0);
      __builtin_amdgcn_global_load_lds(
          (const __attribute__((address_space(1))) uint32_t*)(gB + (size_t)row * C_IN + k0 + sslot * 8),
          (__attribute__((address_space(3))) uint32_t*)(Bs + rbase * QBK),
          16, 0, 0);
    }
    __syncthreads();

    #pragma unroll
    for (int ks = 0; ks < 2; ++ks) {
      s16x8 af[8], bfr[4];
      #pragma unroll
      for (int m = 0; m < 8; ++m) {
        int row = wr * 128 + m * 16 + (lane & 15);
        int slot = (ks * 4 + (lane >> 4)) ^ (row & 7);
        af[m] = *(const s16x8*)&As[row * QBK + slot * 8];
      }
      #pragma unroll
      for (int nn = 0; nn < 4; ++nn) {
        int row = wc * 64 + nn * 16 + (lane & 15);
        int slot = (ks * 4 + (lane >> 4)) ^ (row & 7);
        bfr[nn] = *(const s16x8*)&Bs[row * QBK + slot * 8];
      }
      #pragma unroll
      for (int m = 0; m < 8; ++m)
        #pragma unroll
        for (int nn = 0; nn < 4; ++nn)
          acc[m][nn] = __builtin_amdgcn_mfma_f32_16x16x32_bf16(af[m], bfr[nn], acc[m][nn], 0, 0, 0);
    }
    __syncthreads();
  }

  // Epilogue: wave-private 16x68 f32 staging -> packed bf16 uint2 stores.
  float* ep = (float*)smem + wave * (16 * 68);
  const int erow = lane >> 4;   // 0..3
  const int ecol = lane & 15;
  const float* bias = bb + oy * QBM + wr * 128;
  ushort* outp = kqv + ((size_t)n * 1024 + oy * QBM + wr * 128) * L
               + (size_t)lx * QBN + wc * 64;
  #pragma unroll
  for (int m = 0; m < 8; ++m) {
    #pragma unroll
    for (int nn = 0; nn < 4; ++nn)
      #pragma unroll
      for (int r = 0; r < 4; ++r)
        ep[(erow * 4 + r) * 68 + nn * 16 + ecol] = acc[m][nn][r];
    #pragma unroll
    for (int p = 0; p < 4; ++p) {
      int row = p * 4 + erow;                 // 0..15
      f32x4 v = *(const f32x4*)&ep[row * 68 + ecol * 4];
      float bo = bias[m * 16 + row];
      uint2 pk;
      pk.x = (uint32_t)f2bf(v[0] + bo) | ((uint32_t)f2bf(v[1] + bo) << 16);
      pk.y = (uint32_t)f2bf(v[2] + bo) | ((uint32_t)f2bf(v[3] + bo) << 16);
      *(uint2*)&outp[(size_t)(m * 16 + row) * L + ecol * 4] = pk;
    }
  }
}

// ---------------------------------------------------------------------------
// Reductions
// ---------------------------------------------------------------------------
__device__ inline float blockReduceMax(float v, float* red) {
  #pragma unroll
  for (int off = 32; off > 0; off >>= 1)
    v = fmaxf(v, __shfl_down(v, off, 64));
  int tid = threadIdx.x;
  if ((tid & 63) == 0) red[tid >> 6] = v;
  __syncthreads();
  return fmaxf(fmaxf(red[0], red[1]), fmaxf(red[2], red[3]));
}
__device__ inline float blockReduceSum(float v, float* red) {
  #pragma unroll
  for (int off = 32; off > 0; off >>= 1)
    v += __shfl_down(v, off, 64);
  int tid = threadIdx.x;
  if ((tid & 63) == 0) red[tid >> 6] = v;
  __syncthreads();
  return red[0] + red[1] + red[2] + red[3];
}

// ---------------------------------------------------------------------------
// Kernel 2: K softmax stats over L per (n, row) from bf16 K
// ---------------------------------------------------------------------------
__global__ __launch_bounds__(256) void k_kstats(const ushort* __restrict__ kqv,
                                                float* __restrict__ kmax,
                                                float* __restrict__ kinv)
{
  const int r = blockIdx.x;
  const int n = blockIdx.y;
  const ushort* row = kqv + ((size_t)n * 1024 + r) * L;
  __shared__ float red1[4];
  __shared__ float red2[4];
  const int tid = threadIdx.x;
  s16x8 a = *(const s16x8*)(row + tid * 16);
  s16x8 b = *(const s16x8*)(row + tid * 16 + 8);
  float v[16];
  #pragma unroll
  for (int j = 0; j < 8; ++j) { v[j] = bf2f((ushort)a[j]); v[8 + j] = bf2f((ushort)b[j]); }
  float m = -3.0e38f;
  #pragma unroll
  for (int j = 0; j < 16; ++j) m = fmaxf(m, v[j]);
  m = blockReduceMax(m, red1);
  float s = 0.f;
  #pragma unroll
  for (int j = 0; j < 16; ++j) s += __expf(v[j] - m);
  s = blockReduceSum(s, red2);
  if (tid == 0) { kmax[n * KC + r] = m; kinv[n * KC + r] = 1.0f / s; }
}

// ---------------------------------------------------------------------------
// Kernel 3: Q channel-softmax + transpose: qT[n][l][256] bf16 normalized.
// ---------------------------------------------------------------------------
__global__ __launch_bounds__(256) void k_qT(const ushort* __restrict__ kqv,
                                            ushort* __restrict__ qT)
{
  const int n = blockIdx.z;
  const int h = blockIdx.y;
  const int l = blockIdx.x * 256 + threadIdx.x;
  const ushort* Qb = kqv + ((size_t)n * 1024 + KC + h * HK) * L + l;
  float p[HK];
  float m = -3.0e38f;
  #pragma unroll
  for (int k = 0; k < HK; ++k) {
    float v = bf2f(Qb[(size_t)k * L]);
    p[k] = v;
    m = fmaxf(m, v);
  }
  float s = 0.f;
  #pragma unroll
  for (int k = 0; k < HK; ++k) { p[k] = __expf(p[k] - m); s += p[k]; }
  float inv = 1.0f / s;
  ushort* dst = qT + ((size_t)n * L + l) * KC + h * HK;
  #pragma unroll
  for (int oct = 0; oct < 4; ++oct) {
    s16x8 w;
    #pragma unroll
    for (int j = 0; j < 8; ++j) w[j] = (short)f2bf(p[oct * 8 + j] * inv);
    *(s16x8*)(dst + oct * 8) = w;
  }
}

// ---------------------------------------------------------------------------
// Kernel 4: context partials via MFMA over l.  LDS rows 128B; same XOR
// swizzle (slot^=row&7) on Vs (pre-swizzled gload source) and Ks (ds_write).
// ---------------------------------------------------------------------------
__global__ __launch_bounds__(256) void k_ctx_mfma(const ushort* __restrict__ kqv,
                                                  const float* __restrict__ kmax,
                                                  const float* __restrict__ kinv,
                                                  float* __restrict__ ctxpart)
{
  const int chunk = blockIdx.x;   // 8
  const int nh    = blockIdx.y;   // 128
  const int n = nh >> 3, h = nh & 7;
  const int tid = threadIdx.x, wave = tid >> 6, lane = tid & 63;

  __shared__ __align__(16) ushort Ks[32 * 64];
  __shared__ __align__(16) ushort Vs[64 * 64];
  __shared__ float km[32], kv[32];

  if (tid < 32) { km[tid] = kmax[nh * 32 + tid]; kv[tid] = kinv[nh * 32 + tid]; }
  __syncthreads();

  const ushort* Kp = kqv + ((size_t)n * 1024 + h * HK) * L + (size_t)chunk * CHUNK_L;
  const ushort* Vp = kqv + ((size_t)n * 1024 + 512 + h * HV) * L + (size_t)chunk * CHUNK_L;

  const int krow = tid >> 3;
  const int kslot = (tid & 7) ^ (krow & 7);   // swizzled LDS slot for ds_write
  f32x4 acc[2] = {};

  for (int step = 0; step < 8; ++step) {
    const int l0 = step * 64;
    #pragma unroll
    for (int j = 0; j < 2; ++j) {
      int vr = (j * 4 + wave) * 8 + (lane >> 3);
      int vslot = (lane & 7) ^ (vr & 7);      // pre-swizzled source slot
      __builtin_amdgcn_global_load_lds(
          (const __attribute__((address_space(1))) uint32_t*)(Vp + (size_t)vr * L + l0 + vslot * 8),
          (__attribute__((address_space(3))) uint32_t*)(Vs + (size_t)(j * 4 + wave) * 512),
          16, 0, 0);
    }
    s16x8 kvec = *(const s16x8*)(Kp + (size_t)krow * L + l0 + (tid & 7) * 8);
    float mk = km[krow], ik = kv[krow];
    s16x8 w;
    #pragma unroll
    for (int j = 0; j < 8; ++j) {
      float f = bf2f((ushort)kvec[j]);
      w[j] = (short)f2bf(__expf(f - mk) * ik);
    }
    *(s16x8*)&Ks[krow * 64 + kslot * 8] = w;
    __syncthreads();

    #pragma unroll
    for (int ks = 0; ks < 2; ++ks) {
      int arow = wave * 16 + (lane & 15);
      int aslot = (ks * 4 + (lane >> 4)) ^ (arow & 7);
      s16x8 af = *(const s16x8*)&Vs[arow * 64 + aslot * 8];
      #pragma unroll
      for (int nf = 0; nf < 2; ++nf) {
        int brow = nf * 16 + (lane & 15);
        int bslot = (ks * 4 + (lane >> 4)) ^ (brow & 7);
        s16x8 bfr = *(const s16x8*)&Ks[brow * 64 + bslot * 8];
        acc[nf] = __builtin_amdgcn_mfma_f32_16x16x32_bf16(af, bfr, acc[nf], 0, 0, 0);
      }
    }
    __syncthreads();
  }

  float* outp = ctxpart + ((size_t)nh * CTX_CHUNKS + chunk) * (HV * HK);
  #pragma unroll
  for (int nf = 0; nf < 2; ++nf) {
    #pragma unroll
    for (int r = 0; r < 4; ++r) {
      int v = wave * 16 + (lane >> 4) * 4 + r;
      int k = nf * 16 + (lane & 15);
      outp[v * HK + k] = acc[nf][r];
    }
  }
}

// ---------------------------------------------------------------------------
// Kernel 5: reduce ctx partials; fold We; write bf16 Mbuf [n][512][256]
// ---------------------------------------------------------------------------
__global__ __launch_bounds__(256) void k_m(const float* __restrict__ ctxpart,
                                           const float* __restrict__ We,
                                           ushort* __restrict__ Mbuf)
{
  const int h = blockIdx.x;
  const int n = blockIdx.y;
  const int nh = n * 8 + h;
  const int tid = threadIdx.x;
  __shared__ float ctx[64][32];

  #pragma unroll
  for (int i = 0; i < 8; ++i) {
    int e = tid + i * 256;
    float s = 0.f;
    for (int c = 0; c < CTX_CHUNKS; ++c)
      s += ctxpart[((size_t)nh * CTX_CHUNKS + c) * (HV * HK) + e];
    ((float*)ctx)[e] = s;
  }
  __syncthreads();

  const int k  = tid & 31;
  const int og = tid >> 5;
  for (int j = 0; j < 64; ++j) {
    int o = og * 64 + j;
    const float* we = We + (size_t)o * VC + h * HV;
    float s = 0.f;
    #pragma unroll
    for (int v = 0; v < 64; ++v) s += we[v] * ctx[v][k];
    Mbuf[((size_t)n * 512 + o) * KC + h * HK + k] = f2bf(s);
  }
}

// ---------------------------------------------------------------------------
// Kernel 6: out = x + be + M @ q_smT via MFMA.  M=512, N=4096(l), K=256.
// 128x128 tile, BK=32 (64B LDS rows): swizzle slot^=((row>>1)&3).
// ---------------------------------------------------------------------------
#define BM 128
#define BN 128
#define BK 32

__global__ __launch_bounds__(256) void k_final_mfma(
    const ushort* __restrict__ Mb,   // [n][512][256] bf16
    const ushort* __restrict__ qT,   // [n][4096][256] bf16
    const float* __restrict__ x,
    const float* __restrict__ be,
    float* __restrict__ out)
{
  const int n  = blockIdx.z;
  const int oy = blockIdx.y;   // 4
  const int lx = blockIdx.x;   // 32
  const int tid  = threadIdx.x;
  const int wave = tid >> 6, lane = tid & 63;
  const int wr = wave >> 1, wc = wave & 1;

  __shared__ __align__(16) char smem[17408];
  ushort* As = (ushort*)smem;
  ushort* Bs = (ushort*)(smem + 8192);

  f32x4 acc[4][4] = {};

  const ushort* gA = Mb + ((size_t)n * 512 + oy * BM) * KC;
  const ushort* gB = qT + ((size_t)n * L + lx * BN) * KC;

  const int r0 = wave * 32;
  const int lrow = lane >> 2;

  for (int k0 = 0; k0 < KC; k0 += BK) {
    #pragma unroll
    for (int i = 0; i < 2; ++i) {
      int row = r0 + i * 16 + lrow;
      int sslot = (lane & 3) ^ ((row >> 1) & 3);   // pre-swizzled source slot
      __builtin_amdgcn_global_load_lds(
          (const __attribute__((address_space(1))) uint32_t*)(gA + (size_t)row * KC + k0 + sslot * 8),
          (__attribute__((address_space(3))) uint32_t*)(As + (r0 + i * 16) * BK),
          16, 0, 0);
      __builtin_amdgcn_global_load_lds(
          (const __attribute__((address_space(1))) uint32_t*)(gB + (size_t)row * KC + k0 + sslot * 8),
          (__attribute__((address_space(3))) uint32_t*)(Bs + (r0 + i * 16) * BK),
          16, 0, 0);
    }
    __syncthreads();

    s16x8 af[4], bfr[4];
    #pragma unroll
    for (int m = 0; m < 4; ++m) {
      int row = wr * 64 + m * 16 + (lane & 15);
      int slot = (lane >> 4) ^ ((row >> 1) & 3);
      af[m] = *(const s16x8*)&As[row * BK + slot * 8];
    }
    #pragma unroll
    for (int nn = 0; nn < 4; ++nn) {
      int row = wc * 64 + nn * 16 + (lane & 15);
      int slot = (lane >> 4) ^ ((row >> 1) & 3);
      bfr[nn] = *(const s16x8*)&Bs[row * BK + slot * 8];
    }
    #pragma unroll
    for (int m = 0; m < 4; ++m)
      #pragma unroll
      for (int nn = 0; nn < 4; ++nn)
        acc[m][nn] = __builtin_amdgcn_mfma_f32_16x16x32_bf16(af[m], bfr[nn], acc[m][nn], 0, 0, 0);
    __syncthreads();
  }

  // Epilogue: wave-private 16x68 f32 staging -> float4 x-add + float4 store.
  float* ep = (float*)smem + wave * (16 * 68);
  const int erow = lane >> 4;
  const int ecol = lane & 15;
  const float* bias = be + oy * BM + wr * 64;
  const float* xp = x + ((size_t)n * 512 + oy * BM + wr * 64) * L
                  + (size_t)lx * BN + wc * 64;
  float* op = out + ((size_t)n * 512 + oy * BM + wr * 64) * L
            + (size_t)lx * BN + wc * 64;
  #pragma unroll
  for (int m = 0; m < 4; ++m) {
    #pragma unroll
    for (int nn = 0; nn < 4; ++nn)
      #pragma unroll
      for (int r = 0; r < 4; ++r)
        ep[(erow * 4 + r) * 68 + nn * 16 + ecol] = acc[m][nn][r];
    #pragma unroll
    for (int p = 0; p < 4; ++p) {
      int row = p * 4 + erow;
      f32x4 v = *(const f32x4*)&ep[row * 68 + ecol * 4];
      float bo = bias[m * 16 + row];
      f32x4 xv = *(const f32x4*)&xp[(size_t)(m * 16 + row) * L + ecol * 4];
      v = v + xv + bo;
      *(f32x4*)&op[(size_t)(m * 16 + row) * L + ecol * 4] = v;
    }
  }
}

// ---------------------------------------------------------------------------
extern "C" void kernel_launch(void* const* d_in, const int* in_sizes, int n_in,
                              void* d_out, int out_size, void* d_ws, size_t ws_size,
                              hipStream_t stream)
{
  const float* x  = (const float*)d_in[0];
  const float* Wk = (const float*)d_in[1];
  const float* bk = (const float*)d_in[2];
  const float* Wq = (const float*)d_in[3];
  const float* bq = (const float*)d_in[4];
  const float* Wv = (const float*)d_in[5];
  const float* bv = (const float*)d_in[6];
  const float* We = (const float*)d_in[7];
  const float* be = (const float*)d_in[8];
  float* out = (float*)d_out;

  char* ws = (char*)d_ws;
  size_t off = 0;
  ushort* kqv  = (ushort*)(ws + off); off += (size_t)N_BATCH * 1024 * L * 2;
  ushort* xT   = (ushort*)(ws + off); off += (size_t)N_BATCH * L * C_IN * 2;
  ushort* Wb   = (ushort*)(ws + off); off += (size_t)1024 * C_IN * 2;
  float*  bb   = (float*)(ws + off);  off += (size_t)1024 * 4;
  float*  kmax = (float*)(ws + off);  off += (size_t)N_BATCH * KC * 4;
  float*  kinv = (float*)(ws + off);  off += (size_t)N_BATCH * KC * 4;
  ushort* qT   = (ushort*)(ws + off); off += (size_t)N_BATCH * L * KC * 2;
  float*  ctxp = (float*)(ws + off);  off += (size_t)N_BATCH * NH * CTX_CHUNKS * HV * HK * 4;
  ushort* Mbuf = (ushort*)(ws + off); off += (size_t)N_BATCH * 512 * KC * 2;

  k_prep_w<<<dim3(1024), 256, 0, stream>>>(Wk, bk, Wq, bq, Wv, bv, Wb, bb);
  k_prep_x<<<dim3(64, 8, N_BATCH), 256, 0, stream>>>(x, xT);
  k_qkv_mfma<<<dim3(16, 4, N_BATCH), 512, 0, stream>>>(Wb, xT, bb, kqv);
  k_kstats<<<dim3(KC, N_BATCH), 256, 0, stream>>>(kqv, kmax, kinv);
  k_qT<<<dim3(L / 256, NH, N_BATCH), 256, 0, stream>>>(kqv, qT);
  k_ctx_mfma<<<dim3(CTX_CHUNKS, N_BATCH * NH), 256, 0, stream>>>(kqv, kmax, kinv, ctxp);
  k_m<<<dim3(NH, N_BATCH), 256, 0, stream>>>(ctxp, We, Mbuf);
  k_final_mfma<<<dim3(32, 4, N_BATCH), 256, 0, stream>>>(Mbuf, qT, x, be, out);
}

// Round 6
// 262.348 us; speedup vs baseline: 5.5400x; 1.1540x over previous
//
#include <hip/hip_runtime.h>
#include <cstddef>
#include <cstdint>

#define N_BATCH 16
#define C_IN    512
#define L       4096
#define KC      256
#define VC      512
#define NH      8
#define HK      32   // KC/NH
#define HV      64   // VC/NH
#define CTX_CHUNKS 8
#define CHUNK_L (L / CTX_CHUNKS)  // 512

using f32x4 = __attribute__((ext_vector_type(4))) float;
using s16x8 = __attribute__((ext_vector_type(8))) short;

// round-to-nearest-even fp32 -> bf16 bits
static __device__ inline ushort f2bf(float f) {
  uint32_t u = __float_as_uint(f);
  uint32_t r = (u + 0x7FFFu + ((u >> 16) & 1u)) >> 16;
  return (ushort)r;
}
static __device__ inline float bf2f(ushort u) {
  return __uint_as_float((uint32_t)u << 16);
}

// ---------------------------------------------------------------------------
// Prep 1: combined bf16 weight matrix Wb[1024][512] + combined bias bb[1024]
// ---------------------------------------------------------------------------
__global__ __launch_bounds__(256) void k_prep_w(
    const float* __restrict__ Wk, const float* __restrict__ bk,
    const float* __restrict__ Wq, const float* __restrict__ bq,
    const float* __restrict__ Wv, const float* __restrict__ bv,
    ushort* __restrict__ Wb, float* __restrict__ bb)
{
  const int o = blockIdx.x;          // 1024
  const float* src; const float* bsrc; int oo;
  if (o < 256)      { src = Wk + (size_t)o * C_IN;         bsrc = bk; oo = o; }
  else if (o < 512) { src = Wq + (size_t)(o - 256) * C_IN; bsrc = bq; oo = o - 256; }
  else              { src = Wv + (size_t)(o - 512) * C_IN; bsrc = bv; oo = o - 512; }
  const int t = threadIdx.x;
  Wb[(size_t)o * C_IN + t * 2]     = f2bf(src[t * 2]);
  Wb[(size_t)o * C_IN + t * 2 + 1] = f2bf(src[t * 2 + 1]);
  if (t == 0) bb[o] = bsrc[oo];
}

// ---------------------------------------------------------------------------
// Prep 2: transpose+cast x (n,512,4096) f32 -> xT (n,4096,512) bf16
// ---------------------------------------------------------------------------
__global__ __launch_bounds__(256) void k_prep_x(const float* __restrict__ x,
                                                ushort* __restrict__ xT)
{
  __shared__ float t[64][65];
  const int n = blockIdx.z, cy = blockIdx.y, lx = blockIdx.x;
  const float* xp = x + ((size_t)n * C_IN + cy * 64) * L + (size_t)lx * 64;
  const int l4 = (threadIdx.x & 15) * 4;
  const int c0 = threadIdx.x >> 4;
  #pragma unroll
  for (int i = 0; i < 4; ++i) {
    int cc = c0 + i * 16;
    f32x4 v = *(const f32x4*)&xp[(size_t)cc * L + l4];
    t[cc][l4]     = v[0];
    t[cc][l4 + 1] = v[1];
    t[cc][l4 + 2] = v[2];
    t[cc][l4 + 3] = v[3];
  }
  __syncthreads();
  ushort* op = xT + ((size_t)n * L + lx * 64) * C_IN + cy * 64;
  const int cp = (threadIdx.x & 31) * 2, l0 = threadIdx.x >> 5;
  #pragma unroll
  for (int i = 0; i < 8; ++i) {
    int lr = l0 + i * 8;
    uint32_t pack = (uint32_t)f2bf(t[cp][lr]) | ((uint32_t)f2bf(t[cp + 1][lr]) << 16);
    *(uint32_t*)(op + (size_t)lr * C_IN + cp) = pack;
  }
}

// ---------------------------------------------------------------------------
// Kernel 1: KQV = Wb @ x + bias, bf16 MFMA, 256x256 tile, BK=64, 8 waves.
// 2-phase double-buffered LDS (2 x 64 KB, dynamic): STAGE(t+1) issued before
// compute(t); one barrier per K-tile; setprio around MFMA cluster.
// oy==1 tiles (Q channels) fuse the channel softmax and write qT directly
// (f32 accumulator softmax, shfl_xor(16/32) over the 4 owning lanes).
// ---------------------------------------------------------------------------
#define QBM 256
#define QBN 256
#define QBK 64

__global__ __launch_bounds__(512) void k_qkv_mfma(
    const ushort* __restrict__ Wb,   // [1024][512] bf16
    const ushort* __restrict__ xT,   // [n][4096][512] bf16
    const float* __restrict__ bb,    // [1024]
    ushort* __restrict__ kqv,        // [n][1024][4096] bf16 (K,V rows only)
    ushort* __restrict__ qT)         // [n][4096][256] bf16 (normalized Q^T)
{
  extern __shared__ __align__(16) char smem[];
  const int n  = blockIdx.z;
  const int oy = blockIdx.y;   // 4 row tiles of 256
  const int lx = blockIdx.x;   // 16 col tiles of 256
  const int tid  = threadIdx.x;
  const int wave = tid >> 6, lane = tid & 63;
  const int wr = wave >> 2, wc = wave & 3;   // 2 x 4

  f32x4 acc[8][4] = {};

  const ushort* gA = Wb + (size_t)(oy * QBM) * C_IN;
  const ushort* gB = xT + ((size_t)n * L + lx * QBN) * C_IN;

  const int srow = lane >> 3;              // 0..7
  const int sslotbase = lane & 7;

  // stage K-tile k0 into buffer buf (each thread: 8 gload_lds)
  #define QSTAGE(buf, k0)                                                        \
    {                                                                            \
      ushort* As_ = (ushort*)(smem + (buf) * 65536);                             \
      ushort* Bs_ = (ushort*)(smem + (buf) * 65536 + 32768);                     \
      _Pragma("unroll")                                                          \
      for (int i_ = 0; i_ < 4; ++i_) {                                           \
        int rbase_ = wave * 32 + i_ * 8;                                         \
        int row_ = rbase_ + srow;                                                \
        int ss_ = sslotbase ^ (row_ & 7);                                        \
        __builtin_amdgcn_global_load_lds(                                        \
            (const __attribute__((address_space(1))) uint32_t*)(gA + (size_t)row_ * C_IN + (k0) + ss_ * 8), \
            (__attribute__((address_space(3))) uint32_t*)(As_ + rbase_ * QBK),   \
            16, 0, 0);                                                           \
        __builtin_amdgcn_global_load_lds(                                        \
            (const __attribute__((address_space(1))) uint32_t*)(gB + (size_t)row_ * C_IN + (k0) + ss_ * 8), \
            (__attribute__((address_space(3))) uint32_t*)(Bs_ + rbase_ * QBK),   \
            16, 0, 0);                                                           \
      }                                                                          \
    }

  QSTAGE(0, 0)
  __syncthreads();   // vmcnt(0) drain + barrier (compiler-emitted)

  const int nt = C_IN / QBK;   // 8
  for (int t = 0; t < nt; ++t) {
    if (t < nt - 1) QSTAGE((t + 1) & 1, (t + 1) * QBK)
    ushort* As = (ushort*)(smem + (t & 1) * 65536);
    ushort* Bs = (ushort*)(smem + (t & 1) * 65536 + 32768);
    __builtin_amdgcn_s_setprio(1);
    #pragma unroll
    for (int ks = 0; ks < 2; ++ks) {
      s16x8 af[8], bfr[4];
      #pragma unroll
      for (int m = 0; m < 8; ++m) {
        int row = wr * 128 + m * 16 + (lane & 15);
        int slot = (ks * 4 + (lane >> 4)) ^ (row & 7);
        af[m] = *(const s16x8*)&As[row * QBK + slot * 8];
      }
      #pragma unroll
      for (int nn = 0; nn < 4; ++nn) {
        int row = wc * 64 + nn * 16 + (lane & 15);
        int slot = (ks * 4 + (lane >> 4)) ^ (row & 7);
        bfr[nn] = *(const s16x8*)&Bs[row * QBK + slot * 8];
      }
      #pragma unroll
      for (int m = 0; m < 8; ++m)
        #pragma unroll
        for (int nn = 0; nn < 4; ++nn)
          acc[m][nn] = __builtin_amdgcn_mfma_f32_16x16x32_bf16(af[m], bfr[nn], acc[m][nn], 0, 0, 0);
    }
    __builtin_amdgcn_s_setprio(0);
    __syncthreads();   // drains stage loads (vmcnt 0) + barrier
  }
  #undef QSTAGE

  if (oy != 1) {
    // K / V rows: epilogue via wave-private 16x68 f32 LDS transpose -> uint2
    // bf16 stores.  Last tile used buffer (nt-1)&1 == 1 (offset 65536); ep
    // region at offset 0 is free, wave-private -> no barrier needed.
    float* ep = (float*)smem + wave * (16 * 68);
    const int erow = lane >> 4;   // 0..3
    const int ecol = lane & 15;
    const float* bias = bb + oy * QBM + wr * 128;
    ushort* outp = kqv + ((size_t)n * 1024 + oy * QBM + wr * 128) * L
                 + (size_t)lx * QBN + wc * 64;
    #pragma unroll
    for (int m = 0; m < 8; ++m) {
      #pragma unroll
      for (int nn = 0; nn < 4; ++nn)
        #pragma unroll
        for (int r = 0; r < 4; ++r)
          ep[(erow * 4 + r) * 68 + nn * 16 + ecol] = acc[m][nn][r];
      #pragma unroll
      for (int p = 0; p < 4; ++p) {
        int row = p * 4 + erow;                 // 0..15
        f32x4 v = *(const f32x4*)&ep[row * 68 + ecol * 4];
        float bo = bias[m * 16 + row];
        uint2 pk;
        pk.x = (uint32_t)f2bf(v[0] + bo) | ((uint32_t)f2bf(v[1] + bo) << 16);
        pk.y = (uint32_t)f2bf(v[2] + bo) | ((uint32_t)f2bf(v[3] + bo) << 16);
        *(uint2*)&outp[(size_t)(m * 16 + row) * L + ecol * 4] = pk;
      }
    }
  } else {
    // Q rows: fused channel softmax (over 32 head-channels) -> qT[n][l][256].
    // Channel c = wr*128 + m*16 + (lane>>4)*4 + r; head = wr*4 + (m>>1).
    // At fixed l the head's 32 values live in lanes {lane&15 + 16g}.
    const float* bias = bb + 256 + wr * 128;
    ushort* qbase = qT + (size_t)n * L * KC;
    const int g4 = (lane >> 4) * 4;
    #pragma unroll
    for (int hp = 0; hp < 4; ++hp) {
      const int m0 = 2 * hp, m1 = 2 * hp + 1;
      const float b0_0 = bias[m0 * 16 + g4 + 0], b0_1 = bias[m0 * 16 + g4 + 1];
      const float b0_2 = bias[m0 * 16 + g4 + 2], b0_3 = bias[m0 * 16 + g4 + 3];
      const float b1_0 = bias[m1 * 16 + g4 + 0], b1_1 = bias[m1 * 16 + g4 + 1];
      const float b1_2 = bias[m1 * 16 + g4 + 2], b1_3 = bias[m1 * 16 + g4 + 3];
      #pragma unroll
      for (int nn = 0; nn < 4; ++nn) {
        float v0[4], v1[4];
        v0[0] = acc[m0][nn][0] + b0_0; v0[1] = acc[m0][nn][1] + b0_1;
        v0[2] = acc[m0][nn][2] + b0_2; v0[3] = acc[m0][nn][3] + b0_3;
        v1[0] = acc[m1][nn][0] + b1_0; v1[1] = acc[m1][nn][1] + b1_1;
        v1[2] = acc[m1][nn][2] + b1_2; v1[3] = acc[m1][nn][3] + b1_3;
        float mx = fmaxf(fmaxf(fmaxf(v0[0], v0[1]), fmaxf(v0[2], v0[3])),
                         fmaxf(fmaxf(v1[0], v1[1]), fmaxf(v1[2], v1[3])));
        mx = fmaxf(mx, __shfl_xor(mx, 16));
        mx = fmaxf(mx, __shfl_xor(mx, 32));
        float e0[4], e1[4];
        float s = 0.f;
        #pragma unroll
        for (int r = 0; r < 4; ++r) { e0[r] = __expf(v0[r] - mx); s += e0[r]; }
        #pragma unroll
        for (int r = 0; r < 4; ++r) { e1[r] = __expf(v1[r] - mx); s += e1[r]; }
        s += __shfl_xor(s, 16);
        s += __shfl_xor(s, 32);
        float inv = 1.0f / s;
        int l = lx * QBN + wc * 64 + nn * 16 + (lane & 15);
        ushort* dst = qbase + (size_t)l * KC + wr * 128;
        uint2 p0, p1;
        p0.x = (uint32_t)f2bf(e0[0] * inv) | ((uint32_t)f2bf(e0[1] * inv) << 16);
        p0.y = (uint32_t)f2bf(e0[2] * inv) | ((uint32_t)f2bf(e0[3] * inv) << 16);
        p1.x = (uint32_t)f2bf(e1[0] * inv) | ((uint32_t)f2bf(e1[1] * inv) << 16);
        p1.y = (uint32_t)f2bf(e1[2] * inv) | ((uint32_t)f2bf(e1[3] * inv) << 16);
        *(uint2*)&dst[m0 * 16 + g4] = p0;
        *(uint2*)&dst[m1 * 16 + g4] = p1;
      }
    }
  }
}

// ---------------------------------------------------------------------------
// Reductions
// ---------------------------------------------------------------------------
__device__ inline float blockReduceMax(float v, float* red) {
  #pragma unroll
  for (int off = 32; off > 0; off >>= 1)
    v = fmaxf(v, __shfl_down(v, off, 64));
  int tid = threadIdx.x;
  if ((tid & 63) == 0) red[tid >> 6] = v;
  __syncthreads();
  return fmaxf(fmaxf(red[0], red[1]), fmaxf(red[2], red[3]));
}
__device__ inline float blockReduceSum(float v, float* red) {
  #pragma unroll
  for (int off = 32; off > 0; off >>= 1)
    v += __shfl_down(v, off, 64);
  int tid = threadIdx.x;
  if ((tid & 63) == 0) red[tid >> 6] = v;
  __syncthreads();
  return red[0] + red[1] + red[2] + red[3];
}

// ---------------------------------------------------------------------------
// Kernel 2: K softmax stats over L per (n, row) from bf16 K
// ---------------------------------------------------------------------------
__global__ __launch_bounds__(256) void k_kstats(const ushort* __restrict__ kqv,
                                                float* __restrict__ kmax,
                                                float* __restrict__ kinv)
{
  const int r = blockIdx.x;
  const int n = blockIdx.y;
  const ushort* row = kqv + ((size_t)n * 1024 + r) * L;
  __shared__ float red1[4];
  __shared__ float red2[4];
  const int tid = threadIdx.x;
  s16x8 a = *(const s16x8*)(row + tid * 16);
  s16x8 b = *(const s16x8*)(row + tid * 16 + 8);
  float v[16];
  #pragma unroll
  for (int j = 0; j < 8; ++j) { v[j] = bf2f((ushort)a[j]); v[8 + j] = bf2f((ushort)b[j]); }
  float m = -3.0e38f;
  #pragma unroll
  for (int j = 0; j < 16; ++j) m = fmaxf(m, v[j]);
  m = blockReduceMax(m, red1);
  float s = 0.f;
  #pragma unroll
  for (int j = 0; j < 16; ++j) s += __expf(v[j] - m);
  s = blockReduceSum(s, red2);
  if (tid == 0) { kmax[n * KC + r] = m; kinv[n * KC + r] = 1.0f / s; }
}

// ---------------------------------------------------------------------------
// Kernel 4: context partials via MFMA over l (swizzled LDS)
// ---------------------------------------------------------------------------
__global__ __launch_bounds__(256) void k_ctx_mfma(const ushort* __restrict__ kqv,
                                                  const float* __restrict__ kmax,
                                                  const float* __restrict__ kinv,
                                                  float* __restrict__ ctxpart)
{
  const int chunk = blockIdx.x;   // 8
  const int nh    = blockIdx.y;   // 128
  const int n = nh >> 3, h = nh & 7;
  const int tid = threadIdx.x, wave = tid >> 6, lane = tid & 63;

  __shared__ __align__(16) ushort Ks[32 * 64];
  __shared__ __align__(16) ushort Vs[64 * 64];
  __shared__ float km[32], kv[32];

  if (tid < 32) { km[tid] = kmax[nh * 32 + tid]; kv[tid] = kinv[nh * 32 + tid]; }
  __syncthreads();

  const ushort* Kp = kqv + ((size_t)n * 1024 + h * HK) * L + (size_t)chunk * CHUNK_L;
  const ushort* Vp = kqv + ((size_t)n * 1024 + 512 + h * HV) * L + (size_t)chunk * CHUNK_L;

  const int krow = tid >> 3;
  const int kslot = (tid & 7) ^ (krow & 7);
  f32x4 acc[2] = {};

  for (int step = 0; step < 8; ++step) {
    const int l0 = step * 64;
    #pragma unroll
    for (int j = 0; j < 2; ++j) {
      int vr = (j * 4 + wave) * 8 + (lane >> 3);
      int vslot = (lane & 7) ^ (vr & 7);
      __builtin_amdgcn_global_load_lds(
          (const __attribute__((address_space(1))) uint32_t*)(Vp + (size_t)vr * L + l0 + vslot * 8),
          (__attribute__((address_space(3))) uint32_t*)(Vs + (size_t)(j * 4 + wave) * 512),
          16, 0, 0);
    }
    s16x8 kvec = *(const s16x8*)(Kp + (size_t)krow * L + l0 + (tid & 7) * 8);
    float mk = km[krow], ik = kv[krow];
    s16x8 w;
    #pragma unroll
    for (int j = 0; j < 8; ++j) {
      float f = bf2f((ushort)kvec[j]);
      w[j] = (short)f2bf(__expf(f - mk) * ik);
    }
    *(s16x8*)&Ks[krow * 64 + kslot * 8] = w;
    __syncthreads();

    #pragma unroll
    for (int ks = 0; ks < 2; ++ks) {
      int arow = wave * 16 + (lane & 15);
      int aslot = (ks * 4 + (lane >> 4)) ^ (arow & 7);
      s16x8 af = *(const s16x8*)&Vs[arow * 64 + aslot * 8];
      #pragma unroll
      for (int nf = 0; nf < 2; ++nf) {
        int brow = nf * 16 + (lane & 15);
        int bslot = (ks * 4 + (lane >> 4)) ^ (brow & 7);
        s16x8 bfr = *(const s16x8*)&Ks[brow * 64 + bslot * 8];
        acc[nf] = __builtin_amdgcn_mfma_f32_16x16x32_bf16(af, bfr, acc[nf], 0, 0, 0);
      }
    }
    __syncthreads();
  }

  float* outp = ctxpart + ((size_t)nh * CTX_CHUNKS + chunk) * (HV * HK);
  #pragma unroll
  for (int nf = 0; nf < 2; ++nf) {
    #pragma unroll
    for (int r = 0; r < 4; ++r) {
      int v = wave * 16 + (lane >> 4) * 4 + r;
      int k = nf * 16 + (lane & 15);
      outp[v * HK + k] = acc[nf][r];
    }
  }
}

// ---------------------------------------------------------------------------
// Kernel 5: reduce ctx partials; fold We; write bf16 Mbuf [n][512][256]
// ---------------------------------------------------------------------------
__global__ __launch_bounds__(256) void k_m(const float* __restrict__ ctxpart,
                                           const float* __restrict__ We,
                                           ushort* __restrict__ Mbuf)
{
  const int h = blockIdx.x;
  const int n = blockIdx.y;
  const int nh = n * 8 + h;
  const int tid = threadIdx.x;
  __shared__ float ctx[64][32];

  #pragma unroll
  for (int i = 0; i < 8; ++i) {
    int e = tid + i * 256;
    float s = 0.f;
    for (int c = 0; c < CTX_CHUNKS; ++c)
      s += ctxpart[((size_t)nh * CTX_CHUNKS + c) * (HV * HK) + e];
    ((float*)ctx)[e] = s;
  }
  __syncthreads();

  const int k  = tid & 31;
  const int og = tid >> 5;
  for (int j = 0; j < 64; ++j) {
    int o = og * 64 + j;
    const float* we = We + (size_t)o * VC + h * HV;
    float s = 0.f;
    #pragma unroll
    for (int v = 0; v < 64; ++v) s += we[v] * ctx[v][k];
    Mbuf[((size_t)n * 512 + o) * KC + h * HK + k] = f2bf(s);
  }
}

// ---------------------------------------------------------------------------
// Kernel 6: out = x + be + M @ q_smT via MFMA.  M=512, N=4096(l), K=256.
// 128x128 tile, BK=32, 2-phase double-buffered LDS + setprio.
// ---------------------------------------------------------------------------
#define BM 128
#define BN 128
#define BK 32

__global__ __launch_bounds__(256) void k_final_mfma(
    const ushort* __restrict__ Mb,   // [n][512][256] bf16
    const ushort* __restrict__ qT,   // [n][4096][256] bf16
    const float* __restrict__ x,
    const float* __restrict__ be,
    float* __restrict__ out)
{
  const int n  = blockIdx.z;
  const int oy = blockIdx.y;   // 4
  const int lx = blockIdx.x;   // 32
  const int tid  = threadIdx.x;
  const int wave = tid >> 6, lane = tid & 63;
  const int wr = wave >> 1, wc = wave & 1;

  // 2 x 16 KB double buffer + 17408 B epilogue staging (separate region)
  __shared__ __align__(16) char smem[32768 + 17408];

  f32x4 acc[4][4] = {};

  const ushort* gA = Mb + ((size_t)n * 512 + oy * BM) * KC;
  const ushort* gB = qT + ((size_t)n * L + lx * BN) * KC;

  const int r0 = wave * 32;
  const int lrow = lane >> 2;

  #define FSTAGE(buf, k0)                                                        \
    {                                                                            \
      ushort* As_ = (ushort*)(smem + (buf) * 16384);                             \
      ushort* Bs_ = (ushort*)(smem + (buf) * 16384 + 8192);                      \
      _Pragma("unroll")                                                          \
      for (int i_ = 0; i_ < 2; ++i_) {                                           \
        int row_ = r0 + i_ * 16 + lrow;                                          \
        int ss_ = (lane & 3) ^ ((row_ >> 1) & 3);                                \
        __builtin_amdgcn_global_load_lds(                                        \
            (const __attribute__((address_space(1))) uint32_t*)(gA + (size_t)row_ * KC + (k0) + ss_ * 8), \
            (__attribute__((address_space(3))) uint32_t*)(As_ + (r0 + i_ * 16) * BK), \
            16, 0, 0);                                                           \
        __builtin_amdgcn_global_load_lds(                                        \
            (const __attribute__((address_space(1))) uint32_t*)(gB + (size_t)row_ * KC + (k0) + ss_ * 8), \
            (__attribute__((address_space(3))) uint32_t*)(Bs_ + (r0 + i_ * 16) * BK), \
            16, 0, 0);                                                           \
      }                                                                          \
    }

  FSTAGE(0, 0)
  __syncthreads();

  const int nt = KC / BK;   // 8
  for (int t = 0; t < nt; ++t) {
    if (t < nt - 1) FSTAGE((t + 1) & 1, (t + 1) * BK)
    ushort* As = (ushort*)(smem + (t & 1) * 16384);
    ushort* Bs = (ushort*)(smem + (t & 1) * 16384 + 8192);
    s16x8 af[4], bfr[4];
    #pragma unroll
    for (int m = 0; m < 4; ++m) {
      int row = wr * 64 + m * 16 + (lane & 15);
      int slot = (lane >> 4) ^ ((row >> 1) & 3);
      af[m] = *(const s16x8*)&As[row * BK + slot * 8];
    }
    #pragma unroll
    for (int nn = 0; nn < 4; ++nn) {
      int row = wc * 64 + nn * 16 + (lane & 15);
      int slot = (lane >> 4) ^ ((row >> 1) & 3);
      bfr[nn] = *(const s16x8*)&Bs[row * BK + slot * 8];
    }
    __builtin_amdgcn_s_setprio(1);
    #pragma unroll
    for (int m = 0; m < 4; ++m)
      #pragma unroll
      for (int nn = 0; nn < 4; ++nn)
        acc[m][nn] = __builtin_amdgcn_mfma_f32_16x16x32_bf16(af[m], bfr[nn], acc[m][nn], 0, 0, 0);
    __builtin_amdgcn_s_setprio(0);
    __syncthreads();
  }
  #undef FSTAGE

  // Epilogue: wave-private 16x68 f32 staging -> float4 x-add + float4 store.
  float* ep = (float*)(smem + 32768) + wave * (16 * 68);
  const int erow = lane >> 4;
  const int ecol = lane & 15;
  const float* bias = be + oy * BM + wr * 64;
  const float* xp = x + ((size_t)n * 512 + oy * BM + wr * 64) * L
                  + (size_t)lx * BN + wc * 64;
  float* op = out + ((size_t)n * 512 + oy * BM + wr * 64) * L
            + (size_t)lx * BN + wc * 64;
  #pragma unroll
  for (int m = 0; m < 4; ++m) {
    #pragma unroll
    for (int nn = 0; nn < 4; ++nn)
      #pragma unroll
      for (int r = 0; r < 4; ++r)
        ep[(erow * 4 + r) * 68 + nn * 16 + ecol] = acc[m][nn][r];
    #pragma unroll
    for (int p = 0; p < 4; ++p) {
      int row = p * 4 + erow;
      f32x4 v = *(const f32x4*)&ep[row * 68 + ecol * 4];
      float bo = bias[m * 16 + row];
      f32x4 xv = *(const f32x4*)&xp[(size_t)(m * 16 + row) * L + ecol * 4];
      v = v + xv + bo;
      *(f32x4*)&op[(size_t)(m * 16 + row) * L + ecol * 4] = v;
    }
  }
}

// ---------------------------------------------------------------------------
extern "C" void kernel_launch(void* const* d_in, const int* in_sizes, int n_in,
                              void* d_out, int out_size, void* d_ws, size_t ws_size,
                              hipStream_t stream)
{
  const float* x  = (const float*)d_in[0];
  const float* Wk = (const float*)d_in[1];
  const float* bk = (const float*)d_in[2];
  const float* Wq = (const float*)d_in[3];
  const float* bq = (const float*)d_in[4];
  const float* Wv = (const float*)d_in[5];
  const float* bv = (const float*)d_in[6];
  const float* We = (const float*)d_in[7];
  const float* be = (const float*)d_in[8];
  float* out = (float*)d_out;

  char* ws = (char*)d_ws;
  size_t off = 0;
  ushort* kqv  = (ushort*)(ws + off); off += (size_t)N_BATCH * 1024 * L * 2;
  ushort* xT   = (ushort*)(ws + off); off += (size_t)N_BATCH * L * C_IN * 2;
  ushort* Wb   = (ushort*)(ws + off); off += (size_t)1024 * C_IN * 2;
  float*  bb   = (float*)(ws + off);  off += (size_t)1024 * 4;
  float*  kmax = (float*)(ws + off);  off += (size_t)N_BATCH * KC * 4;
  float*  kinv = (float*)(ws + off);  off += (size_t)N_BATCH * KC * 4;
  ushort* qT   = (ushort*)(ws + off); off += (size_t)N_BATCH * L * KC * 2;
  float*  ctxp = (float*)(ws + off);  off += (size_t)N_BATCH * NH * CTX_CHUNKS * HV * HK * 4;
  ushort* Mbuf = (ushort*)(ws + off); off += (size_t)N_BATCH * 512 * KC * 2;

  static bool attr_done = false;
  if (!attr_done) {
    (void)hipFuncSetAttribute((const void*)k_qkv_mfma,
                              hipFuncAttributeMaxDynamicSharedMemorySize, 131072);
    attr_done = true;
  }

  k_prep_w<<<dim3(1024), 256, 0, stream>>>(Wk, bk, Wq, bq, Wv, bv, Wb, bb);
  k_prep_x<<<dim3(64, 8, N_BATCH), 256, 0, stream>>>(x, xT);
  k_qkv_mfma<<<dim3(16, 4, N_BATCH), 512, 131072, stream>>>(Wb, xT, bb, kqv, qT);
  k_kstats<<<dim3(KC, N_BATCH), 256, 0, stream>>>(kqv, kmax, kinv);
  k_ctx_mfma<<<dim3(CTX_CHUNKS, N_BATCH * NH), 256, 0, stream>>>(kqv, kmax, kinv, ctxp);
  k_m<<<dim3(NH, N_BATCH), 256, 0, stream>>>(ctxp, We, Mbuf);
  k_final_mfma<<<dim3(32, 4, N_BATCH), 256, 0, stream>>>(Mbuf, qT, x, be, out);
}